// Round 7
// baseline (353.007 us; speedup 1.0000x reference)
//
#include <hip/hip_runtime.h>
#include <cstdint>

#define NGRAPH 128
#define NEG 0.2f
#define NB_MAX 512      // buckets of 256 dst nodes; N=100K -> 391 buckets
#define BSH 8           // bucket shift
#define BSZ 256         // bucket size
#define CAP 8192        // bbuf slots per bucket (expected max ~4800)

typedef unsigned int uint;
typedef unsigned short ushort;
typedef unsigned char uchar;
typedef __attribute__((ext_vector_type(8))) short bf16x8;
typedef __attribute__((ext_vector_type(4))) float f32x4;
typedef __attribute__((ext_vector_type(2))) float f32x2;

union U4B { uint4 u; bf16x8 v; };

__device__ __forceinline__ ushort f2bf(float f) {
  uint u = __float_as_uint(f);
  uint r = (u + 0x7FFF + ((u >> 16) & 1)) >> 16;   // RNE
  return (ushort)r;
}

// hardware packed bf16 convert (RNE, bit-identical to f2bf) — 1 instr for 2 ch
__device__ __forceinline__ uint cvtpkbf16(float lo, float hi) {
  uint r;
  asm("v_cvt_pk_bf16_f32 %0, %1, %2" : "=v"(r) : "v"(lo), "v"(hi));
  return r;
}

// packed dual f32 FMA: acc = f * w + acc (VOP3P, 1 instr for 2 ch)
__device__ __forceinline__ void pkfma(f32x2& acc, f32x2 f, f32x2 w) {
  asm("v_pk_fma_f32 %0, %1, %2, %0" : "+v"(acc) : "v"(f), "v"(w));
}

__device__ __forceinline__ float bperm_f(int addr, float v) {
  return __int_as_float(__builtin_amdgcn_ds_bpermute(addr, __float_as_int(v)));
}
__device__ __forceinline__ int bperm_i(int addr, int v) {
  return __builtin_amdgcn_ds_bpermute(addr, v);
}

__device__ __forceinline__ int wave_incl_scan_i(int v) {
  int lane = threadIdx.x & 63;
#pragma unroll
  for (int off = 1; off < 64; off <<= 1) {
    int u = __shfl_up(v, off, 64);
    if (lane >= off) v += u;
  }
  return v;
}

// ---------------- k_bin: LDS hist -> bucket alloc -> scatter; + per-node deg; + W1/W2 prep ----------------
// pass 1 caches the chunk's packed records in LDS; pass 2 scatters from LDS (no ei re-read).
// also counts per-node degree via global atomics (k_bg then needs only ONE bbuf pass).
__global__ void k_bin(const int* __restrict__ ei,
                      const float* __restrict__ W1, const float* __restrict__ W2,
                      ushort* __restrict__ Wt1, ushort* __restrict__ Wt2,
                      int E, int Etot, int NB, int nbin,
                      int* __restrict__ bcur, uint* __restrict__ bbuf,
                      int* __restrict__ gdeg) {
  if (blockIdx.x >= (uint)nbin) {
    int t2 = (blockIdx.x - nbin) * 256 + threadIdx.x;
    if (t2 < 16384) {
      int n = t2 >> 7, k = t2 & 127;
      Wt1[t2] = f2bf(W1[k * 128 + n]);
    } else {
      int u = t2 - 16384;
      int n = u >> 7, k = u & 127;
      Wt2[u] = f2bf(W2[k * 32 + n]);
    }
    return;
  }
  __shared__ int h[NB_MAX];
  __shared__ int baseo[NB_MAX];
  __shared__ uint crec[4096];     // packed (d_local<<17)|s
  __shared__ ushort cbkt[4096];   // bucket id
  int t = threadIdx.x;
  for (int b = t; b < NB; b += 256) h[b] = 0;
  __syncthreads();
  int cbase = blockIdx.x * 4096;
  int cend = min(cbase + 4096, Etot);
  int nch = cend - cbase;
  for (int i = t; i < nch; i += 256) {
    int e = cbase + i;
    int s, d;
    if (e < E) {
      s = __builtin_nontemporal_load(&ei[e]);
      d = __builtin_nontemporal_load(&ei[E + e]);
    } else { s = e - E; d = s; }
    int b = d >> BSH;
    crec[i] = ((uint)(d & (BSZ - 1)) << 17) | (uint)s;
    cbkt[i] = (ushort)b;
    atomicAdd(&h[b], 1);
    atomicAdd(&gdeg[d], 1);
  }
  __syncthreads();
  for (int b = t; b < NB; b += 256) {
    int c = h[b];
    baseo[b] = c ? atomicAdd(&bcur[b], c) : 0;
    h[b] = 0;
  }
  __syncthreads();
  for (int i = t; i < nch; i += 256) {
    int b = cbkt[i];
    int r = atomicAdd(&h[b], 1);
    bbuf[(size_t)b * CAP + baseo[b] + r] = crec[i];
  }
}

// ---------------- k_bg: blocks [0,NB) = CSR build (single scatter pass); blocks [NB,..) = GEMM1+att1 ----------------
__global__ void k_bg(const uint* __restrict__ bbuf, const int* __restrict__ bcur,
                     const int* __restrict__ gdeg,
                     int NB, int N, int* __restrict__ offs, int* __restrict__ ssrc,
                     const float* __restrict__ x, const ushort* __restrict__ Wt,
                     const float* __restrict__ nw, const float* __restrict__ att_s,
                     const float* __restrict__ att_d, uchar* __restrict__ hb1,
                     float* __restrict__ asrc, float* __restrict__ adst) {
  __shared__ int sst[NB_MAX + 1];
  __shared__ int wsum2[4];
  __shared__ int cur[BSZ];
  if (blockIdx.x < (uint)NB) {
    int t = threadIdx.x, lane = t & 63, wid = t >> 6;
    int v0 = (2 * t < NB) ? bcur[2 * t] : 0;
    int v1 = (2 * t + 1 < NB) ? bcur[2 * t + 1] : 0;
    int s = v0 + v1;
    int sv = wave_incl_scan_i(s);
    if (lane == 63) wsum2[wid] = sv;
    __syncthreads();
    if (t == 0) {
      int r = 0;
#pragma unroll
      for (int k = 0; k < 4; k++) { int x2 = wsum2[k]; wsum2[k] = r; r += x2; }
    }
    __syncthreads();
    int excl = wsum2[wid] + sv - s;
    sst[2 * t] = excl;
    sst[2 * t + 1] = excl + v0;
    if (t == 255) sst[512] = excl + v0 + v1;
    __syncthreads();       // sst ready; all wsum2 reads done
    int b = blockIdx.x;
    int ebeg = sst[b], eend = sst[b + 1];
    int cnt = eend - ebeg;
    const uint* brow = bbuf + (size_t)b * CAP;
    // per-node scan of global degree (no bbuf hist pass needed)
    int node = (b << BSH) + t;
    int v = (node < N) ? gdeg[node] : 0;
    int sv2 = wave_incl_scan_i(v);
    if (lane == 63) wsum2[wid] = sv2;
    __syncthreads();
    if (t == 0) {
      int r = 0;
#pragma unroll
      for (int k = 0; k < 4; k++) { int x2 = wsum2[k]; wsum2[k] = r; r += x2; }
    }
    __syncthreads();
    int excl2 = wsum2[wid] + sv2 - v;
    if (node < N) offs[node] = ebeg + excl2;
    if (b == 0 && t == 0) offs[N] = sst[512];
    cur[t] = excl2;
    __syncthreads();
    // single scatter pass over the bucket
    for (int i = t; i < cnt; i += BSZ) {
      uint rec = brow[i];
      int r = atomicAdd(&cur[rec >> 17], 1);
      ssrc[ebeg + r] = (int)(rec & 0x1FFFF);
    }
    return;
  }
  // ---- gemm1 path (operand-swapped MFMA: D[channel][node]) ----
  int bid = blockIdx.x - NB;
  int wv = threadIdx.x >> 6, l = threadIdx.x & 63;
  int lg = l >> 4, lr = l & 15;
  int row0 = bid * 64 + wv * 16;
  int node = row0 + lr;
  bool valid = node < N;
  float sc = valid ? nw[node] : 0.f;
  bf16x8 xfr[4];
  const float* xr = x + (size_t)node * 128;
#pragma unroll
  for (int kc = 0; kc < 4; kc++) {
    float v[8];
    if (valid) {
      f32x4 q0 = __builtin_nontemporal_load(reinterpret_cast<const f32x4*>(xr + kc * 32 + lg * 8));
      f32x4 q1 = __builtin_nontemporal_load(reinterpret_cast<const f32x4*>(xr + kc * 32 + lg * 8 + 4));
      v[0] = q0[0]; v[1] = q0[1]; v[2] = q0[2]; v[3] = q0[3];
      v[4] = q1[0]; v[5] = q1[1]; v[6] = q1[2]; v[7] = q1[3];
    } else {
#pragma unroll
      for (int j = 0; j < 8; j++) v[j] = 0.f;
    }
    U4B a;
    a.u.x = cvtpkbf16(v[0] * sc, v[1] * sc);
    a.u.y = cvtpkbf16(v[2] * sc, v[3] * sc);
    a.u.z = cvtpkbf16(v[4] * sc, v[5] * sc);
    a.u.w = cvtpkbf16(v[6] * sc, v[7] * sc);
    xfr[kc] = a.v;
  }
  float pS[4] = {}, pD[4] = {};
#pragma unroll
  for (int ct = 0; ct < 8; ct++) {
    f32x4 acc = {0.f, 0.f, 0.f, 0.f};
    const ushort* wrow = Wt + (size_t)(ct * 16 + lr) * 128;
#pragma unroll
    for (int kc = 0; kc < 4; kc++) {
      U4B bfr;
      bfr.u = *reinterpret_cast<const uint4*>(wrow + kc * 32 + lg * 8);
      acc = __builtin_amdgcn_mfma_f32_16x16x32_bf16(bfr.v, xfr[kc], acc, 0, 0, 0);
    }
    int c0 = ct * 16 + lg * 4;
    if (valid) {
      uint u8 = (uint)__builtin_amdgcn_cvt_pk_fp8_f32(acc[0], acc[1], 0, false);
      u8 = (uint)__builtin_amdgcn_cvt_pk_fp8_f32(acc[2], acc[3], u8, true);
      *reinterpret_cast<uint*>(hb1 + (size_t)node * 128 + c0) = u8;
    }
    float4 as4 = *reinterpret_cast<const float4*>(att_s + c0);
    float4 ad4 = *reinterpret_cast<const float4*>(att_d + c0);
    int h = ct >> 1;
    pS[h] += acc[0] * as4.x + acc[1] * as4.y + acc[2] * as4.z + acc[3] * as4.w;
    pD[h] += acc[0] * ad4.x + acc[1] * ad4.y + acc[2] * ad4.z + acc[3] * ad4.w;
  }
#pragma unroll
  for (int off = 16; off < 64; off <<= 1) {
#pragma unroll
    for (int h = 0; h < 4; h++) {
      pS[h] += __shfl_xor(pS[h], off, 64);
      pD[h] += __shfl_xor(pD[h], off, 64);
    }
  }
  if (lg == 0 && valid) {
    *reinterpret_cast<float4*>(asrc + node * 4) = make_float4(pS[0], pS[1], pS[2], pS[3]);
    *reinterpret_cast<float4*>(adst + node * 4) = make_float4(pD[0], pD[1], pD[2], pD[3]);
  }
}

// ---- fused layer-1 aggregation + layer-2 GEMM (MFMA, wave-0 tail) + att2 ----
// chunked schedule: phase A computes 32 edge-weights wave-wide (lane = edge x head),
// phase B bpermutes s/w and keeps 4 row loads in flight.
// layer-2 output goes into 64-B packed records: [32B fp8 row | 4B asrc2 | pad].
__global__ void k_aggr1(const int* __restrict__ offs, const int* __restrict__ ssrc,
                        const uchar* __restrict__ hb, const float* __restrict__ asrc,
                        const float* __restrict__ adst, const float* __restrict__ bias,
                        const ushort* __restrict__ Wt2, const float* __restrict__ as2,
                        const float* __restrict__ ad2, uchar* __restrict__ rec2,
                        float* __restrict__ adst2, int N) {
  __shared__ ushort rowl[4][136];    // bf16 out1 rows, +8 pad
  int tid = threadIdx.x;
  int wv = tid >> 6, l = tid & 63;
  int d = blockIdx.x * 4 + wv;
  int dc = min(d, N - 1);
  int slot = l >> 3;       // 0..7 edge slot (phase B)
  int cb = l & 7;          // channel block: ch cb*16 .. +15
  int h = cb >> 1;         // head of this lane's channels
  int hq = l & 3;          // phase-A head
  int eidx = l >> 2;       // phase-A edge-in-chunk 0..15
  float adq = adst[dc * 4 + hq];
  int beg = offs[dc], end = offs[dc + 1];
  int endm1 = end - 1;
  const uchar* hbc = hb + cb * 16;
  int bp0 = (slot * 4 + h) << 2;   // bpermute byte addr, edge slot (it even)
  int bp1 = bp0 + 128;             // +32 lanes (it odd)
  f32x2 a2[8] = {};
  float dsp = 0.f;
  auto ACC = [&](uint4 p, float w) {
    f32x2 wp = {w, w};
    f32x2 f;
    f = __builtin_amdgcn_cvt_pk_f32_fp8(p.x, false); pkfma(a2[0], f, wp);
    f = __builtin_amdgcn_cvt_pk_f32_fp8(p.x, true);  pkfma(a2[1], f, wp);
    f = __builtin_amdgcn_cvt_pk_f32_fp8(p.y, false); pkfma(a2[2], f, wp);
    f = __builtin_amdgcn_cvt_pk_f32_fp8(p.y, true);  pkfma(a2[3], f, wp);
    f = __builtin_amdgcn_cvt_pk_f32_fp8(p.z, false); pkfma(a2[4], f, wp);
    f = __builtin_amdgcn_cvt_pk_f32_fp8(p.z, true);  pkfma(a2[5], f, wp);
    f = __builtin_amdgcn_cvt_pk_f32_fp8(p.w, false); pkfma(a2[6], f, wp);
    f = __builtin_amdgcn_cvt_pk_f32_fp8(p.w, true);  pkfma(a2[7], f, wp);
  };
  for (int base = beg; base < end; base += 32) {
    // ---- phase A: 32 edge-weights, lane = (edge 0..15) x (head 0..3) ----
    int eA = base + eidx;
    int eB = eA + 16;
    int sA = ssrc[min(eA, endm1)];
    int sB = ssrc[min(eB, endm1)];
    // s redistribution does not depend on exp -> issue row loads early
    int s0 = bperm_i(bp0, sA);
    int s1 = bperm_i(bp1, sA);
    int s2 = bperm_i(bp0, sB);
    int s3 = bperm_i(bp1, sB);
    int rem = end - base;
    uint4 p0, p1, p2, p3;
    p0 = *reinterpret_cast<const uint4*>(hbc + (size_t)s0 * 128);
    if (rem > 8)  p1 = *reinterpret_cast<const uint4*>(hbc + (size_t)s1 * 128);
    if (rem > 16) p2 = *reinterpret_cast<const uint4*>(hbc + (size_t)s2 * 128);
    if (rem > 24) p3 = *reinterpret_cast<const uint4*>(hbc + (size_t)s3 * 128);
    float aA = asrc[sA * 4 + hq] + adq;     // coalesced 16B across 4 head lanes
    float aB = asrc[sB * 4 + hq] + adq;
    aA = fmaxf(aA, aA * NEG);
    aB = fmaxf(aB, aB * NEG);
    float wA = (eA < end) ? __expf(aA) : 0.f;
    float wB = (eB < end) ? __expf(aB) : 0.f;
    dsp += wA + wB;
    float w0 = bperm_f(bp0, wA);
    float w1 = bperm_f(bp1, wA);
    float w2 = bperm_f(bp0, wB);
    float w3 = bperm_f(bp1, wB);
    // ---- phase B: consume (guards are wave-uniform) ----
    ACC(p0, w0);
    if (rem > 8)  ACC(p1, w1);
    if (rem > 16) ACC(p2, w2);
    if (rem > 24) ACC(p3, w3);
  }
  // softmax denominator: sum over stride-4 lane groups (per head), then broadcast
  dsp += __shfl_xor(dsp, 4, 64);
  dsp += __shfl_xor(dsp, 8, 64);
  dsp += __shfl_xor(dsp, 16, 64);
  dsp += __shfl_xor(dsp, 32, 64);
  float ds = bperm_f(h << 2, dsp);
  int b3 = (l >> 3) & 1, b4 = (l >> 4) & 1, b5 = (l >> 5) & 1;
  float t8[8];
#pragma unroll
  for (int r = 0; r < 8; r++) {
    float av = a2[r >> 1][r & 1];
    float bv = a2[(r + 8) >> 1][r & 1];
    float send = b3 ? av : bv;
    float recv = __shfl_xor(send, 8, 64);
    t8[r] = (b3 ? bv : av) + recv;
  }
  float t4[4];
#pragma unroll
  for (int r = 0; r < 4; r++) {
    float send = b4 ? t8[r] : t8[r + 4];
    float recv = __shfl_xor(send, 16, 64);
    t4[r] = (b4 ? t8[r + 4] : t8[r]) + recv;
  }
  float t2[2];
#pragma unroll
  for (int r = 0; r < 2; r++) {
    float send = b5 ? t4[r] : t4[r + 2];
    float recv = __shfl_xor(send, 32, 64);
    t2[r] = (b5 ? t4[r + 2] : t4[r]) + recv;
  }
  float inv = __builtin_amdgcn_rcpf(ds > 0.f ? ds : 1.f);
  int c0 = cb * 16 + b3 * 8 + b4 * 4 + b5 * 2;
  float2 bi = *reinterpret_cast<const float2*>(bias + c0);
  float r0 = fmaf(t2[0], inv, bi.x);
  float r1 = fmaf(t2[1], inv, bi.y);
  r0 = r0 > 0.f ? r0 : __expf(r0) - 1.f;   // elu via exp (abs err ~1e-7)
  r1 = r1 > 0.f ? r1 : __expf(r1) - 1.f;
  *reinterpret_cast<uint*>(&rowl[wv][c0]) = cvtpkbf16(r0, r1);
  __syncthreads();
  if (wv != 0) return;
  // ---- gemm2 + att2 on the block's 4 rows (wave 0 only) ----
  int lg = l >> 4, lr = l & 15;
  int rsel = lr & 3;
  bf16x8 bfrag[4];
#pragma unroll
  for (int kc = 0; kc < 4; kc++) {
    U4B bb;
    bb.u = *reinterpret_cast<const uint4*>(&rowl[rsel][kc * 32 + lg * 8]);
    bfrag[kc] = bb.v;
  }
  int dd = blockIdx.x * 4 + lr;      // valid only for lr<4
  bool vs = (lr < 4) && (dd < N);
  float pS = 0.f, pD = 0.f;
#pragma unroll
  for (int ct = 0; ct < 2; ct++) {
    f32x4 acc = {0.f, 0.f, 0.f, 0.f};
    const ushort* wrow = Wt2 + (size_t)(ct * 16 + lr) * 128;
#pragma unroll
    for (int kc = 0; kc < 4; kc++) {
      U4B bfr;
      bfr.u = *reinterpret_cast<const uint4*>(wrow + kc * 32 + lg * 8);
      acc = __builtin_amdgcn_mfma_f32_16x16x32_bf16(bfr.v, bfrag[kc], acc, 0, 0, 0);
    }
    int cg = ct * 16 + lg * 4;
    if (vs) {
      uint u8 = (uint)__builtin_amdgcn_cvt_pk_fp8_f32(acc[0], acc[1], 0, false);
      u8 = (uint)__builtin_amdgcn_cvt_pk_fp8_f32(acc[2], acc[3], u8, true);
      *reinterpret_cast<uint*>(rec2 + (size_t)dd * 64 + cg) = u8;
    }
    float4 as4 = *reinterpret_cast<const float4*>(as2 + cg);
    float4 ad4 = *reinterpret_cast<const float4*>(ad2 + cg);
    pS += acc[0] * as4.x + acc[1] * as4.y + acc[2] * as4.z + acc[3] * as4.w;
    pD += acc[0] * ad4.x + acc[1] * ad4.y + acc[2] * ad4.z + acc[3] * ad4.w;
  }
  pS += __shfl_xor(pS, 16, 64);
  pS += __shfl_xor(pS, 32, 64);
  pD += __shfl_xor(pD, 16, 64);
  pD += __shfl_xor(pD, 32, 64);
  if (vs && lg == 0) {
    *reinterpret_cast<float*>(rec2 + (size_t)dd * 64 + 32) = pS;
    adst2[dd] = pD;
  }
}

// ---- layer-2 aggregation + in-kernel graph pooling ----
// 64-B packed records: phase-A asrc load warms the line phase-B's row load hits.
// Per-block LDS pooling (batch sorted -> <=4 graph slots), then atomics into gsum.
__global__ void k_aggr2(const int* __restrict__ offs, const int* __restrict__ ssrc,
                        const uchar* __restrict__ rec, const float* __restrict__ adst,
                        const float* __restrict__ bias, const int* __restrict__ batch,
                        float* __restrict__ gsum, int N) {
  __shared__ float sblk[4][32];
  int tid = threadIdx.x;
  int wid = tid >> 6, l = tid & 63;
  if (tid < 128) sblk[tid >> 5][tid & 31] = 0.f;
  __syncthreads();
  int d = blockIdx.x * 4 + wid;
  bool valid = d < N;
  int dc = valid ? d : N - 1;
  int slot = l >> 2;       // 0..15 edge slot (phase B)
  int k = l & 3;           // channel block: ch k*8 .. +7
  float ad = adst[dc];
  int beg = offs[dc];
  int end = valid ? offs[dc + 1] : beg;
  int endm1 = end - 1;
  const uchar* rk = rec + k * 8;
  int bq0 = slot << 2;
  int bq1 = (slot + 16) << 2;
  int bq2 = (slot + 32) << 2;
  int bq3 = (slot + 48) << 2;
  f32x2 a2[4] = {};
  float dsp = 0.f;
  auto ACC2 = [&](uint2 p, float w) {
    f32x2 wp = {w, w};
    f32x2 f;
    f = __builtin_amdgcn_cvt_pk_f32_fp8(p.x, false); pkfma(a2[0], f, wp);
    f = __builtin_amdgcn_cvt_pk_f32_fp8(p.x, true);  pkfma(a2[1], f, wp);
    f = __builtin_amdgcn_cvt_pk_f32_fp8(p.y, false); pkfma(a2[2], f, wp);
    f = __builtin_amdgcn_cvt_pk_f32_fp8(p.y, true);  pkfma(a2[3], f, wp);
  };
  for (int base = beg; base < end; base += 64) {
    // phase A: 64 edge-weights, one per lane; asrc packed at row+32 warms the line
    int e = base + l;
    int sL = ssrc[min(e, endm1)];
    int s0 = bperm_i(bq0, sL);
    int s1 = bperm_i(bq1, sL);
    int s2 = bperm_i(bq2, sL);
    int s3 = bperm_i(bq3, sL);
    int rem = end - base;
    float av = *reinterpret_cast<const float*>(rec + (size_t)sL * 64 + 32);
    uint2 p0, p1, p2, p3;
    p0 = *reinterpret_cast<const uint2*>(rk + (size_t)s0 * 64);
    if (rem > 16) p1 = *reinterpret_cast<const uint2*>(rk + (size_t)s1 * 64);
    if (rem > 32) p2 = *reinterpret_cast<const uint2*>(rk + (size_t)s2 * 64);
    if (rem > 48) p3 = *reinterpret_cast<const uint2*>(rk + (size_t)s3 * 64);
    float xv = av + ad;
    xv = fmaxf(xv, xv * NEG);
    float wL = (e < end) ? __expf(xv) : 0.f;
    dsp += wL;
    float w0 = bperm_f(bq0, wL);
    float w1 = bperm_f(bq1, wL);
    float w2 = bperm_f(bq2, wL);
    float w3 = bperm_f(bq3, wL);
    ACC2(p0, w0);
    if (rem > 16) ACC2(p1, w1);
    if (rem > 32) ACC2(p2, w2);
    if (rem > 48) ACC2(p3, w3);
  }
  dsp += __shfl_xor(dsp, 1, 64);
  dsp += __shfl_xor(dsp, 2, 64);
  dsp += __shfl_xor(dsp, 4, 64);
  dsp += __shfl_xor(dsp, 8, 64);
  dsp += __shfl_xor(dsp, 16, 64);
  dsp += __shfl_xor(dsp, 32, 64);
  int b2 = (l >> 2) & 1, b3 = (l >> 3) & 1, b4 = (l >> 4) & 1;
  float t4[4];
#pragma unroll
  for (int r = 0; r < 4; r++) {
    float av = a2[r >> 1][r & 1];
    float bv = a2[(r + 4) >> 1][r & 1];
    float send = b2 ? av : bv;
    float recv = __shfl_xor(send, 4, 64);
    t4[r] = (b2 ? bv : av) + recv;
  }
  float t2[2];
#pragma unroll
  for (int r = 0; r < 2; r++) {
    float send = b3 ? t4[r] : t4[r + 2];
    float recv = __shfl_xor(send, 8, 64);
    t2[r] = (b3 ? t4[r + 2] : t4[r]) + recv;
  }
  float send = b4 ? t2[0] : t2[1];
  float recv = __shfl_xor(send, 16, 64);
  float t1 = (b4 ? t2[1] : t2[0]) + recv;
  t1 += __shfl_xor(t1, 32, 64);
  int gfirst = batch[blockIdx.x * 4];     // first node of block always < N
  if (l < 32 && valid) {
    int c = k * 8 + b2 * 4 + b3 * 2 + b4;
    float inv = __builtin_amdgcn_rcpf(dsp > 0.f ? dsp : 1.f);
    float r = fmaf(t1, inv, bias[c]);
    r = r > 0.f ? r : __expf(r) - 1.f;
    int g = batch[dc];
    int sl = g - gfirst;
    if (sl < 4) atomicAdd(&sblk[sl][c], r);
    else atomicAdd(&gsum[g * 32 + c], r);   // rare: >4 graphs in one block
  }
  __syncthreads();
  if (tid < 128) {
    int sl = tid >> 5, c = tid & 31;
    float v = sblk[sl][c];
    int gg = gfirst + sl;
    if (v != 0.f && gg < NGRAPH) atomicAdd(&gsum[gg * 32 + c], v);
  }
}

// ---------------- k_fc: pooled mean (from gsum + binary-search counts) + FC ----------------
__global__ void k_fc(const float* __restrict__ gsum, const int* __restrict__ batch,
                     const float* __restrict__ fcW, const float* __restrict__ fcb,
                     float* __restrict__ out, int N) {
  int g = blockIdx.x;
  int l = threadIdx.x;
  int lo = 0, hi = N;
  while (lo < hi) { int mid = (lo + hi) >> 1; if (batch[mid] < g) lo = mid + 1; else hi = mid; }
  int beg = lo;
  hi = N;
  while (lo < hi) { int mid = (lo + hi) >> 1; if (batch[mid] < g + 1) lo = mid + 1; else hi = mid; }
  int end = lo;
  float inv = 1.f / fmaxf((float)(end - beg), 1.f);
  __shared__ float pooled[32];
  if (l < 32) pooled[l] = gsum[g * 32 + l] * inv;
  __syncthreads();
  if (l < 16) {
    float r = fcb[l];
#pragma unroll
    for (int cc = 0; cc < 32; cc++) r += pooled[cc] * fcW[cc * 16 + l];
    out[g * 16 + l] = r;
  }
}

// ---------------- host launch ----------------
extern "C" void kernel_launch(void* const* d_in, const int* in_sizes, int n_in,
                              void* d_out, int out_size, void* d_ws, size_t ws_size,
                              hipStream_t stream) {
  const float* x     = (const float*)d_in[0];
  const int*   ei    = (const int*)d_in[1];
  const int*   batch = (const int*)d_in[2];
  const float* nw    = (const float*)d_in[3];
  const float* W1    = (const float*)d_in[4];
  const float* as1w  = (const float*)d_in[5];
  const float* ad1w  = (const float*)d_in[6];
  const float* b1    = (const float*)d_in[7];
  const float* W2    = (const float*)d_in[8];
  const float* as2w  = (const float*)d_in[9];
  const float* ad2w  = (const float*)d_in[10];
  const float* b2    = (const float*)d_in[11];
  const float* fcW   = (const float*)d_in[12];
  const float* fcb   = (const float*)d_in[13];
  float* out = (float*)d_out;

  const int N = in_sizes[0] / 128;
  const int E = in_sizes[1] / 2;
  const int Etot = E + N;
  const int NB = (N + BSZ - 1) >> BSH;

  char* w = (char*)d_ws;
  size_t ofs = 0;
  auto alloc = [&](size_t bytes) {
    char* p = w + ofs;
    ofs += (bytes + 255) & ~(size_t)255;
    return p;
  };
  uchar*  hb1    = (uchar*)alloc((size_t)N * 128);        // fp8 layer-1 features
  uchar*  rec2   = (uchar*)alloc((size_t)N * 64);         // [32B fp8 row | 4B asrc2 | pad]
  float*  asrc1  = (float*)alloc((size_t)N * 4 * 4);
  float*  adst1  = (float*)alloc((size_t)N * 4 * 4);
  float*  adst2  = (float*)alloc((size_t)N * 4);
  ushort* Wt1    = (ushort*)alloc(16384 * 2);
  ushort* Wt2    = (ushort*)alloc(4096 * 2);
  int*    bcur   = (int*)alloc((size_t)NB * 4);
  float*  gsum   = (float*)alloc((size_t)NGRAPH * 32 * 4);
  int*    gdeg   = (int*)alloc((size_t)N * 4);
  int*    offs   = (int*)alloc((size_t)(N + 1) * 4);
  uint*   bbuf   = (uint*)alloc((size_t)NB * CAP * 4);
  int*    ssrc   = (int*)alloc((size_t)Etot * 4);

  // one memset zeroes bcur + gsum + gdeg (allocated adjacently)
  size_t zlen = (size_t)((char*)gdeg - (char*)bcur) + (size_t)N * 4;
  hipMemsetAsync(bcur, 0, zlen, stream);

  // binned scatter + per-node degree (+W1/W2 prep folded in)
  const int nbin = (Etot + 4095) / 4096;
  k_bin<<<nbin + 80, 256, 0, stream>>>(ei, W1, W2, Wt1, Wt2, E, Etot, NB, nbin,
                                       bcur, bbuf, gdeg);

  // build ‖ gemm1 (independent): blocks [0,NB) build CSR (single pass), rest run GEMM1+att1
  const int ngemm1 = (N + 63) / 64;
  k_bg<<<NB + ngemm1, 256, 0, stream>>>(bbuf, bcur, gdeg, NB, N, offs, ssrc,
                                        x, Wt1, nw, as1w, ad1w, hb1, asrc1, adst1);

  // fused: layer-1 aggregation + layer-2 GEMM (MFMA) + att2 -> packed rec2
  k_aggr1<<<(N + 3) / 4, 256, 0, stream>>>(offs, ssrc, hb1, asrc1, adst1, b1,
                                           Wt2, as2w, ad2w, rec2, adst2, N);

  // layer-2 aggregation + in-kernel pooling
  k_aggr2<<<(N + 3) / 4, 256, 0, stream>>>(offs, ssrc, rec2, adst2, b2, batch, gsum, N);

  // pooled mean + fc (tiny)
  k_fc<<<NGRAPH, 64, 0, stream>>>(gsum, batch, fcW, fcb, out, N);
}

// Round 8
// 305.690 us; speedup vs baseline: 1.1548x; 1.1548x over previous
//
#include <hip/hip_runtime.h>
#include <cstdint>

#define NGRAPH 128
#define NEG 0.2f
#define NB_MAX 512      // buckets of 256 dst nodes; N=100K -> 391 buckets
#define BSH 8           // bucket shift
#define BSZ 256         // bucket size
#define CAP 8192        // bbuf slots per bucket (expected max ~4800)
#define CH  2048        // k_bin chunk size (2048 -> 830 blocks, 15KB LDS)

typedef unsigned int uint;
typedef unsigned short ushort;
typedef unsigned char uchar;
typedef __attribute__((ext_vector_type(8))) short bf16x8;
typedef __attribute__((ext_vector_type(4))) float f32x4;
typedef __attribute__((ext_vector_type(2))) float f32x2;

union U4B { uint4 u; bf16x8 v; };

__device__ __forceinline__ ushort f2bf(float f) {
  uint u = __float_as_uint(f);
  uint r = (u + 0x7FFF + ((u >> 16) & 1)) >> 16;   // RNE
  return (ushort)r;
}

// hardware packed bf16 convert (RNE, bit-identical to f2bf) — 1 instr for 2 ch
__device__ __forceinline__ uint cvtpkbf16(float lo, float hi) {
  uint r;
  asm("v_cvt_pk_bf16_f32 %0, %1, %2" : "=v"(r) : "v"(lo), "v"(hi));
  return r;
}

// packed dual f32 FMA: acc = f * w + acc (VOP3P, 1 instr for 2 ch)
__device__ __forceinline__ void pkfma(f32x2& acc, f32x2 f, f32x2 w) {
  asm("v_pk_fma_f32 %0, %1, %2, %0" : "+v"(acc) : "v"(f), "v"(w));
}

__device__ __forceinline__ float bperm_f(int addr, float v) {
  return __int_as_float(__builtin_amdgcn_ds_bpermute(addr, __float_as_int(v)));
}
__device__ __forceinline__ int bperm_i(int addr, int v) {
  return __builtin_amdgcn_ds_bpermute(addr, v);
}

__device__ __forceinline__ int wave_incl_scan_i(int v) {
  int lane = threadIdx.x & 63;
#pragma unroll
  for (int off = 1; off < 64; off <<= 1) {
    int u = __shfl_up(v, off, 64);
    if (lane >= off) v += u;
  }
  return v;
}

// ---------------- k_bin: per-block LDS hist -> bucket alloc -> scatter; + W1/W2 prep ----------------
// pass 1 caches the chunk's packed records in LDS; pass 2 scatters from LDS (no ei re-read).
// chunk=2048 for 2x block parallelism (k_bin is latency-bound, R7 counters).
__global__ void k_bin(const int* __restrict__ ei,
                      const float* __restrict__ W1, const float* __restrict__ W2,
                      ushort* __restrict__ Wt1, ushort* __restrict__ Wt2,
                      int E, int Etot, int NB, int nbin,
                      int* __restrict__ bcur, uint* __restrict__ bbuf) {
  if (blockIdx.x >= (uint)nbin) {
    int t2 = (blockIdx.x - nbin) * 256 + threadIdx.x;
    if (t2 < 16384) {
      int n = t2 >> 7, k = t2 & 127;
      Wt1[t2] = f2bf(W1[k * 128 + n]);
    } else {
      int u = t2 - 16384;
      int n = u >> 7, k = u & 127;
      Wt2[u] = f2bf(W2[k * 32 + n]);
    }
    return;
  }
  __shared__ int h[NB_MAX];
  __shared__ int baseo[NB_MAX];
  __shared__ uint crec[CH];     // packed (d_local<<17)|s
  __shared__ ushort cbkt[CH];   // bucket id
  int t = threadIdx.x;
  for (int b = t; b < NB; b += 256) h[b] = 0;
  __syncthreads();
  int cbase = blockIdx.x * CH;
  int cend = min(cbase + CH, Etot);
  int nch = cend - cbase;
  for (int i = t; i < nch; i += 256) {
    int e = cbase + i;
    int s, d;
    if (e < E) {
      s = __builtin_nontemporal_load(&ei[e]);
      d = __builtin_nontemporal_load(&ei[E + e]);
    } else { s = e - E; d = s; }
    int b = d >> BSH;
    crec[i] = ((uint)(d & (BSZ - 1)) << 17) | (uint)s;
    cbkt[i] = (ushort)b;
    atomicAdd(&h[b], 1);
  }
  __syncthreads();
  for (int b = t; b < NB; b += 256) {
    int c = h[b];
    baseo[b] = c ? atomicAdd(&bcur[b], c) : 0;
    h[b] = 0;
  }
  __syncthreads();
  for (int i = t; i < nch; i += 256) {
    int b = cbkt[i];
    int r = atomicAdd(&h[b], 1);
    bbuf[(size_t)b * CAP + baseo[b] + r] = crec[i];
  }
}

// ---------------- k_bg: blocks [0,NB) = CSR build; blocks [NB,..) = GEMM1+att1 ----------------
// CSR half: 2-pass over the bucket (hist then scatter); bucket is <=32KB so pass 2 hits L2.
// No LDS record cache: keeps static LDS at ~3KB so gemm1-path blocks get 8 blocks/CU.
__global__ void k_bg(const uint* __restrict__ bbuf, const int* __restrict__ bcur,
                     int NB, int N, int* __restrict__ offs, int* __restrict__ ssrc,
                     const float* __restrict__ x, const ushort* __restrict__ Wt,
                     const float* __restrict__ nw, const float* __restrict__ att_s,
                     const float* __restrict__ att_d, uchar* __restrict__ hb1,
                     float* __restrict__ asrc, float* __restrict__ adst) {
  __shared__ int sst[NB_MAX + 1];
  __shared__ int wsum2[4];
  __shared__ int deg[BSZ];
  if (blockIdx.x < (uint)NB) {
    int t = threadIdx.x, lane = t & 63, wid = t >> 6;
    int v0 = (2 * t < NB) ? bcur[2 * t] : 0;
    int v1 = (2 * t + 1 < NB) ? bcur[2 * t + 1] : 0;
    int s = v0 + v1;
    int sv = wave_incl_scan_i(s);
    if (lane == 63) wsum2[wid] = sv;
    deg[t] = 0;
    __syncthreads();
    if (t == 0) {
      int r = 0;
#pragma unroll
      for (int k = 0; k < 4; k++) { int x2 = wsum2[k]; wsum2[k] = r; r += x2; }
    }
    __syncthreads();
    int excl = wsum2[wid] + sv - s;
    sst[2 * t] = excl;
    sst[2 * t + 1] = excl + v0;
    if (t == 255) sst[512] = excl + v0 + v1;
    __syncthreads();
    int b = blockIdx.x;
    int ebeg = sst[b], eend = sst[b + 1];
    int cnt = eend - ebeg;
    const uint* brow = bbuf + (size_t)b * CAP;
    for (int i = t; i < cnt; i += BSZ)
      atomicAdd(&deg[brow[i] >> 17], 1);
    __syncthreads();
    int v = deg[t];
    int sv2 = wave_incl_scan_i(v);
    if (lane == 63) wsum2[wid] = sv2;
    __syncthreads();
    if (t == 0) {
      int r = 0;
#pragma unroll
      for (int k = 0; k < 4; k++) { int x2 = wsum2[k]; wsum2[k] = r; r += x2; }
    }
    __syncthreads();
    int excl2 = wsum2[wid] + sv2 - v;
    int node = (b << BSH) + t;
    if (node < N) offs[node] = ebeg + excl2;
    if (b == 0 && t == 0) offs[N] = sst[512];
    __syncthreads();
    deg[t] = excl2;
    __syncthreads();
    for (int i = t; i < cnt; i += BSZ) {
      uint rec = brow[i];
      int r = atomicAdd(&deg[rec >> 17], 1);
      ssrc[ebeg + r] = (int)(rec & 0x1FFFF);
    }
    return;
  }
  // ---- gemm1 path (operand-swapped MFMA: D[channel][node]) ----
  int bid = blockIdx.x - NB;
  int wv = threadIdx.x >> 6, l = threadIdx.x & 63;
  int lg = l >> 4, lr = l & 15;
  int row0 = bid * 64 + wv * 16;
  int node = row0 + lr;
  bool valid = node < N;
  float sc = valid ? nw[node] : 0.f;
  bf16x8 xfr[4];
  const float* xr = x + (size_t)node * 128;
#pragma unroll
  for (int kc = 0; kc < 4; kc++) {
    float v[8];
    if (valid) {
      f32x4 q0 = __builtin_nontemporal_load(reinterpret_cast<const f32x4*>(xr + kc * 32 + lg * 8));
      f32x4 q1 = __builtin_nontemporal_load(reinterpret_cast<const f32x4*>(xr + kc * 32 + lg * 8 + 4));
      v[0] = q0[0]; v[1] = q0[1]; v[2] = q0[2]; v[3] = q0[3];
      v[4] = q1[0]; v[5] = q1[1]; v[6] = q1[2]; v[7] = q1[3];
    } else {
#pragma unroll
      for (int j = 0; j < 8; j++) v[j] = 0.f;
    }
    U4B a;
    a.u.x = cvtpkbf16(v[0] * sc, v[1] * sc);
    a.u.y = cvtpkbf16(v[2] * sc, v[3] * sc);
    a.u.z = cvtpkbf16(v[4] * sc, v[5] * sc);
    a.u.w = cvtpkbf16(v[6] * sc, v[7] * sc);
    xfr[kc] = a.v;
  }
  float pS[4] = {}, pD[4] = {};
#pragma unroll
  for (int ct = 0; ct < 8; ct++) {
    f32x4 acc = {0.f, 0.f, 0.f, 0.f};
    const ushort* wrow = Wt + (size_t)(ct * 16 + lr) * 128;
#pragma unroll
    for (int kc = 0; kc < 4; kc++) {
      U4B bfr;
      bfr.u = *reinterpret_cast<const uint4*>(wrow + kc * 32 + lg * 8);
      acc = __builtin_amdgcn_mfma_f32_16x16x32_bf16(bfr.v, xfr[kc], acc, 0, 0, 0);
    }
    int c0 = ct * 16 + lg * 4;
    if (valid) {
      uint u8 = (uint)__builtin_amdgcn_cvt_pk_fp8_f32(acc[0], acc[1], 0, false);
      u8 = (uint)__builtin_amdgcn_cvt_pk_fp8_f32(acc[2], acc[3], u8, true);
      *reinterpret_cast<uint*>(hb1 + (size_t)node * 128 + c0) = u8;
    }
    float4 as4 = *reinterpret_cast<const float4*>(att_s + c0);
    float4 ad4 = *reinterpret_cast<const float4*>(att_d + c0);
    int h = ct >> 1;
    pS[h] += acc[0] * as4.x + acc[1] * as4.y + acc[2] * as4.z + acc[3] * as4.w;
    pD[h] += acc[0] * ad4.x + acc[1] * ad4.y + acc[2] * ad4.z + acc[3] * ad4.w;
  }
#pragma unroll
  for (int off = 16; off < 64; off <<= 1) {
#pragma unroll
    for (int h = 0; h < 4; h++) {
      pS[h] += __shfl_xor(pS[h], off, 64);
      pD[h] += __shfl_xor(pD[h], off, 64);
    }
  }
  if (lg == 0 && valid) {
    *reinterpret_cast<float4*>(asrc + node * 4) = make_float4(pS[0], pS[1], pS[2], pS[3]);
    *reinterpret_cast<float4*>(adst + node * 4) = make_float4(pD[0], pD[1], pD[2], pD[3]);
  }
}

// ---- fused layer-1 aggregation + layer-2 GEMM (MFMA, wave-0 tail) + att2 ----
// chunked schedule: phase A computes 32 edge-weights wave-wide (lane = edge x head),
// phase B bpermutes s/w and keeps 4 row loads in flight.
// layer-2 output goes into 64-B packed records: [32B fp8 row | 4B asrc2 | pad].
__global__ void k_aggr1(const int* __restrict__ offs, const int* __restrict__ ssrc,
                        const uchar* __restrict__ hb, const float* __restrict__ asrc,
                        const float* __restrict__ adst, const float* __restrict__ bias,
                        const ushort* __restrict__ Wt2, const float* __restrict__ as2,
                        const float* __restrict__ ad2, uchar* __restrict__ rec2,
                        float* __restrict__ adst2, int N) {
  __shared__ ushort rowl[4][136];    // bf16 out1 rows, +8 pad
  int tid = threadIdx.x;
  int wv = tid >> 6, l = tid & 63;
  int d = blockIdx.x * 4 + wv;
  int dc = min(d, N - 1);
  int slot = l >> 3;       // 0..7 edge slot (phase B)
  int cb = l & 7;          // channel block: ch cb*16 .. +15
  int h = cb >> 1;         // head of this lane's channels
  int hq = l & 3;          // phase-A head
  int eidx = l >> 2;       // phase-A edge-in-chunk 0..15
  float adq = adst[dc * 4 + hq];
  int beg = offs[dc], end = offs[dc + 1];
  int endm1 = end - 1;
  const uchar* hbc = hb + cb * 16;
  int bp0 = (slot * 4 + h) << 2;   // bpermute byte addr, edge slot (it even)
  int bp1 = bp0 + 128;             // +32 lanes (it odd)
  f32x2 a2[8] = {};
  float dsp = 0.f;
  auto ACC = [&](uint4 p, float w) {
    f32x2 wp = {w, w};
    f32x2 f;
    f = __builtin_amdgcn_cvt_pk_f32_fp8(p.x, false); pkfma(a2[0], f, wp);
    f = __builtin_amdgcn_cvt_pk_f32_fp8(p.x, true);  pkfma(a2[1], f, wp);
    f = __builtin_amdgcn_cvt_pk_f32_fp8(p.y, false); pkfma(a2[2], f, wp);
    f = __builtin_amdgcn_cvt_pk_f32_fp8(p.y, true);  pkfma(a2[3], f, wp);
    f = __builtin_amdgcn_cvt_pk_f32_fp8(p.z, false); pkfma(a2[4], f, wp);
    f = __builtin_amdgcn_cvt_pk_f32_fp8(p.z, true);  pkfma(a2[5], f, wp);
    f = __builtin_amdgcn_cvt_pk_f32_fp8(p.w, false); pkfma(a2[6], f, wp);
    f = __builtin_amdgcn_cvt_pk_f32_fp8(p.w, true);  pkfma(a2[7], f, wp);
  };
  for (int base = beg; base < end; base += 32) {
    // ---- phase A: 32 edge-weights, lane = (edge 0..15) x (head 0..3) ----
    int eA = base + eidx;
    int eB = eA + 16;
    int sA = ssrc[min(eA, endm1)];
    int sB = ssrc[min(eB, endm1)];
    // s redistribution does not depend on exp -> issue row loads early
    int s0 = bperm_i(bp0, sA);
    int s1 = bperm_i(bp1, sA);
    int s2 = bperm_i(bp0, sB);
    int s3 = bperm_i(bp1, sB);
    int rem = end - base;
    uint4 p0, p1, p2, p3;
    p0 = *reinterpret_cast<const uint4*>(hbc + (size_t)s0 * 128);
    if (rem > 8)  p1 = *reinterpret_cast<const uint4*>(hbc + (size_t)s1 * 128);
    if (rem > 16) p2 = *reinterpret_cast<const uint4*>(hbc + (size_t)s2 * 128);
    if (rem > 24) p3 = *reinterpret_cast<const uint4*>(hbc + (size_t)s3 * 128);
    float aA = asrc[sA * 4 + hq] + adq;     // coalesced 16B across 4 head lanes
    float aB = asrc[sB * 4 + hq] + adq;
    aA = fmaxf(aA, aA * NEG);
    aB = fmaxf(aB, aB * NEG);
    float wA = (eA < end) ? __expf(aA) : 0.f;
    float wB = (eB < end) ? __expf(aB) : 0.f;
    dsp += wA + wB;
    float w0 = bperm_f(bp0, wA);
    float w1 = bperm_f(bp1, wA);
    float w2 = bperm_f(bp0, wB);
    float w3 = bperm_f(bp1, wB);
    // ---- phase B: consume (guards are wave-uniform) ----
    ACC(p0, w0);
    if (rem > 8)  ACC(p1, w1);
    if (rem > 16) ACC(p2, w2);
    if (rem > 24) ACC(p3, w3);
  }
  // softmax denominator: sum over stride-4 lane groups (per head), then broadcast
  dsp += __shfl_xor(dsp, 4, 64);
  dsp += __shfl_xor(dsp, 8, 64);
  dsp += __shfl_xor(dsp, 16, 64);
  dsp += __shfl_xor(dsp, 32, 64);
  float ds = bperm_f(h << 2, dsp);
  int b3 = (l >> 3) & 1, b4 = (l >> 4) & 1, b5 = (l >> 5) & 1;
  float t8[8];
#pragma unroll
  for (int r = 0; r < 8; r++) {
    float av = a2[r >> 1][r & 1];
    float bv = a2[(r + 8) >> 1][r & 1];
    float send = b3 ? av : bv;
    float recv = __shfl_xor(send, 8, 64);
    t8[r] = (b3 ? bv : av) + recv;
  }
  float t4[4];
#pragma unroll
  for (int r = 0; r < 4; r++) {
    float send = b4 ? t8[r] : t8[r + 4];
    float recv = __shfl_xor(send, 16, 64);
    t4[r] = (b4 ? t8[r + 4] : t8[r]) + recv;
  }
  float t2[2];
#pragma unroll
  for (int r = 0; r < 2; r++) {
    float send = b5 ? t4[r] : t4[r + 2];
    float recv = __shfl_xor(send, 32, 64);
    t2[r] = (b5 ? t4[r + 2] : t4[r]) + recv;
  }
  float inv = __builtin_amdgcn_rcpf(ds > 0.f ? ds : 1.f);
  int c0 = cb * 16 + b3 * 8 + b4 * 4 + b5 * 2;
  float2 bi = *reinterpret_cast<const float2*>(bias + c0);
  float r0 = fmaf(t2[0], inv, bi.x);
  float r1 = fmaf(t2[1], inv, bi.y);
  r0 = r0 > 0.f ? r0 : __expf(r0) - 1.f;   // elu via exp (abs err ~1e-7)
  r1 = r1 > 0.f ? r1 : __expf(r1) - 1.f;
  *reinterpret_cast<uint*>(&rowl[wv][c0]) = cvtpkbf16(r0, r1);
  __syncthreads();
  if (wv != 0) return;
  // ---- gemm2 + att2 on the block's 4 rows (wave 0 only) ----
  int lg = l >> 4, lr = l & 15;
  int rsel = lr & 3;
  bf16x8 bfrag[4];
#pragma unroll
  for (int kc = 0; kc < 4; kc++) {
    U4B bb;
    bb.u = *reinterpret_cast<const uint4*>(&rowl[rsel][kc * 32 + lg * 8]);
    bfrag[kc] = bb.v;
  }
  int dd = blockIdx.x * 4 + lr;      // valid only for lr<4
  bool vs = (lr < 4) && (dd < N);
  float pS = 0.f, pD = 0.f;
#pragma unroll
  for (int ct = 0; ct < 2; ct++) {
    f32x4 acc = {0.f, 0.f, 0.f, 0.f};
    const ushort* wrow = Wt2 + (size_t)(ct * 16 + lr) * 128;
#pragma unroll
    for (int kc = 0; kc < 4; kc++) {
      U4B bfr;
      bfr.u = *reinterpret_cast<const uint4*>(wrow + kc * 32 + lg * 8);
      acc = __builtin_amdgcn_mfma_f32_16x16x32_bf16(bfr.v, bfrag[kc], acc, 0, 0, 0);
    }
    int cg = ct * 16 + lg * 4;
    if (vs) {
      uint u8 = (uint)__builtin_amdgcn_cvt_pk_fp8_f32(acc[0], acc[1], 0, false);
      u8 = (uint)__builtin_amdgcn_cvt_pk_fp8_f32(acc[2], acc[3], u8, true);
      *reinterpret_cast<uint*>(rec2 + (size_t)dd * 64 + cg) = u8;
    }
    float4 as4 = *reinterpret_cast<const float4*>(as2 + cg);
    float4 ad4 = *reinterpret_cast<const float4*>(ad2 + cg);
    pS += acc[0] * as4.x + acc[1] * as4.y + acc[2] * as4.z + acc[3] * as4.w;
    pD += acc[0] * ad4.x + acc[1] * ad4.y + acc[2] * ad4.z + acc[3] * ad4.w;
  }
  pS += __shfl_xor(pS, 16, 64);
  pS += __shfl_xor(pS, 32, 64);
  pD += __shfl_xor(pD, 16, 64);
  pD += __shfl_xor(pD, 32, 64);
  if (vs && lg == 0) {
    *reinterpret_cast<float*>(rec2 + (size_t)dd * 64 + 32) = pS;
    adst2[dd] = pD;
  }
}

// ---- layer-2 aggregation + in-kernel graph pooling ----
// 64-B packed records: phase-A asrc load warms the line phase-B's row load hits.
// Per-block LDS pooling (batch sorted -> <=4 graph slots), then atomics into gsum.
__global__ void k_aggr2(const int* __restrict__ offs, const int* __restrict__ ssrc,
                        const uchar* __restrict__ rec, const float* __restrict__ adst,
                        const float* __restrict__ bias, const int* __restrict__ batch,
                        float* __restrict__ gsum, int N) {
  __shared__ float sblk[4][32];
  int tid = threadIdx.x;
  int wid = tid >> 6, l = tid & 63;
  if (tid < 128) sblk[tid >> 5][tid & 31] = 0.f;
  __syncthreads();
  int d = blockIdx.x * 4 + wid;
  bool valid = d < N;
  int dc = valid ? d : N - 1;
  int slot = l >> 2;       // 0..15 edge slot (phase B)
  int k = l & 3;           // channel block: ch k*8 .. +7
  float ad = adst[dc];
  int beg = offs[dc];
  int end = valid ? offs[dc + 1] : beg;
  int endm1 = end - 1;
  const uchar* rk = rec + k * 8;
  int bq0 = slot << 2;
  int bq1 = (slot + 16) << 2;
  int bq2 = (slot + 32) << 2;
  int bq3 = (slot + 48) << 2;
  f32x2 a2[4] = {};
  float dsp = 0.f;
  auto ACC2 = [&](uint2 p, float w) {
    f32x2 wp = {w, w};
    f32x2 f;
    f = __builtin_amdgcn_cvt_pk_f32_fp8(p.x, false); pkfma(a2[0], f, wp);
    f = __builtin_amdgcn_cvt_pk_f32_fp8(p.x, true);  pkfma(a2[1], f, wp);
    f = __builtin_amdgcn_cvt_pk_f32_fp8(p.y, false); pkfma(a2[2], f, wp);
    f = __builtin_amdgcn_cvt_pk_f32_fp8(p.y, true);  pkfma(a2[3], f, wp);
  };
  for (int base = beg; base < end; base += 64) {
    // phase A: 64 edge-weights, one per lane; asrc packed at row+32 warms the line
    int e = base + l;
    int sL = ssrc[min(e, endm1)];
    int s0 = bperm_i(bq0, sL);
    int s1 = bperm_i(bq1, sL);
    int s2 = bperm_i(bq2, sL);
    int s3 = bperm_i(bq3, sL);
    int rem = end - base;
    float av = *reinterpret_cast<const float*>(rec + (size_t)sL * 64 + 32);
    uint2 p0, p1, p2, p3;
    p0 = *reinterpret_cast<const uint2*>(rk + (size_t)s0 * 64);
    if (rem > 16) p1 = *reinterpret_cast<const uint2*>(rk + (size_t)s1 * 64);
    if (rem > 32) p2 = *reinterpret_cast<const uint2*>(rk + (size_t)s2 * 64);
    if (rem > 48) p3 = *reinterpret_cast<const uint2*>(rk + (size_t)s3 * 64);
    float xv = av + ad;
    xv = fmaxf(xv, xv * NEG);
    float wL = (e < end) ? __expf(xv) : 0.f;
    dsp += wL;
    float w0 = bperm_f(bq0, wL);
    float w1 = bperm_f(bq1, wL);
    float w2 = bperm_f(bq2, wL);
    float w3 = bperm_f(bq3, wL);
    ACC2(p0, w0);
    if (rem > 16) ACC2(p1, w1);
    if (rem > 32) ACC2(p2, w2);
    if (rem > 48) ACC2(p3, w3);
  }
  dsp += __shfl_xor(dsp, 1, 64);
  dsp += __shfl_xor(dsp, 2, 64);
  dsp += __shfl_xor(dsp, 4, 64);
  dsp += __shfl_xor(dsp, 8, 64);
  dsp += __shfl_xor(dsp, 16, 64);
  dsp += __shfl_xor(dsp, 32, 64);
  int b2 = (l >> 2) & 1, b3 = (l >> 3) & 1, b4 = (l >> 4) & 1;
  float t4[4];
#pragma unroll
  for (int r = 0; r < 4; r++) {
    float av = a2[r >> 1][r & 1];
    float bv = a2[(r + 4) >> 1][r & 1];
    float send = b2 ? av : bv;
    float recv = __shfl_xor(send, 4, 64);
    t4[r] = (b2 ? bv : av) + recv;
  }
  float t2[2];
#pragma unroll
  for (int r = 0; r < 2; r++) {
    float send = b3 ? t4[r] : t4[r + 2];
    float recv = __shfl_xor(send, 8, 64);
    t2[r] = (b3 ? t4[r + 2] : t4[r]) + recv;
  }
  float send = b4 ? t2[0] : t2[1];
  float recv = __shfl_xor(send, 16, 64);
  float t1 = (b4 ? t2[1] : t2[0]) + recv;
  t1 += __shfl_xor(t1, 32, 64);
  int gfirst = batch[blockIdx.x * 4];     // first node of block always < N
  if (l < 32 && valid) {
    int c = k * 8 + b2 * 4 + b3 * 2 + b4;
    float inv = __builtin_amdgcn_rcpf(dsp > 0.f ? dsp : 1.f);
    float r = fmaf(t1, inv, bias[c]);
    r = r > 0.f ? r : __expf(r) - 1.f;
    int g = batch[dc];
    int sl = g - gfirst;
    if (sl < 4) atomicAdd(&sblk[sl][c], r);
    else atomicAdd(&gsum[g * 32 + c], r);   // rare: >4 graphs in one block
  }
  __syncthreads();
  if (tid < 128) {
    int sl = tid >> 5, c = tid & 31;
    float v = sblk[sl][c];
    int gg = gfirst + sl;
    if (v != 0.f && gg < NGRAPH) atomicAdd(&gsum[gg * 32 + c], v);
  }
}

// ---------------- k_fc: pooled mean (from gsum + binary-search counts) + FC ----------------
__global__ void k_fc(const float* __restrict__ gsum, const int* __restrict__ batch,
                     const float* __restrict__ fcW, const float* __restrict__ fcb,
                     float* __restrict__ out, int N) {
  int g = blockIdx.x;
  int l = threadIdx.x;
  int lo = 0, hi = N;
  while (lo < hi) { int mid = (lo + hi) >> 1; if (batch[mid] < g) lo = mid + 1; else hi = mid; }
  int beg = lo;
  hi = N;
  while (lo < hi) { int mid = (lo + hi) >> 1; if (batch[mid] < g + 1) lo = mid + 1; else hi = mid; }
  int end = lo;
  float inv = 1.f / fmaxf((float)(end - beg), 1.f);
  __shared__ float pooled[32];
  if (l < 32) pooled[l] = gsum[g * 32 + l] * inv;
  __syncthreads();
  if (l < 16) {
    float r = fcb[l];
#pragma unroll
    for (int cc = 0; cc < 32; cc++) r += pooled[cc] * fcW[cc * 16 + l];
    out[g * 16 + l] = r;
  }
}

// ---------------- host launch ----------------
extern "C" void kernel_launch(void* const* d_in, const int* in_sizes, int n_in,
                              void* d_out, int out_size, void* d_ws, size_t ws_size,
                              hipStream_t stream) {
  const float* x     = (const float*)d_in[0];
  const int*   ei    = (const int*)d_in[1];
  const int*   batch = (const int*)d_in[2];
  const float* nw    = (const float*)d_in[3];
  const float* W1    = (const float*)d_in[4];
  const float* as1w  = (const float*)d_in[5];
  const float* ad1w  = (const float*)d_in[6];
  const float* b1    = (const float*)d_in[7];
  const float* W2    = (const float*)d_in[8];
  const float* as2w  = (const float*)d_in[9];
  const float* ad2w  = (const float*)d_in[10];
  const float* b2    = (const float*)d_in[11];
  const float* fcW   = (const float*)d_in[12];
  const float* fcb   = (const float*)d_in[13];
  float* out = (float*)d_out;

  const int N = in_sizes[0] / 128;
  const int E = in_sizes[1] / 2;
  const int Etot = E + N;
  const int NB = (N + BSZ - 1) >> BSH;

  char* w = (char*)d_ws;
  size_t ofs = 0;
  auto alloc = [&](size_t bytes) {
    char* p = w + ofs;
    ofs += (bytes + 255) & ~(size_t)255;
    return p;
  };
  uchar*  hb1    = (uchar*)alloc((size_t)N * 128);        // fp8 layer-1 features
  uchar*  rec2   = (uchar*)alloc((size_t)N * 64);         // [32B fp8 row | 4B asrc2 | pad]
  float*  asrc1  = (float*)alloc((size_t)N * 4 * 4);
  float*  adst1  = (float*)alloc((size_t)N * 4 * 4);
  float*  adst2  = (float*)alloc((size_t)N * 4);
  ushort* Wt1    = (ushort*)alloc(16384 * 2);
  ushort* Wt2    = (ushort*)alloc(4096 * 2);
  int*    bcur   = (int*)alloc((size_t)NB * 4);
  float*  gsum   = (float*)alloc((size_t)NGRAPH * 32 * 4);
  int*    offs   = (int*)alloc((size_t)(N + 1) * 4);
  uint*   bbuf   = (uint*)alloc((size_t)NB * CAP * 4);
  int*    ssrc   = (int*)alloc((size_t)Etot * 4);

  // one memset zeroes bcur + gsum (allocated adjacently)
  size_t zlen = (size_t)((char*)gsum - (char*)bcur) + (size_t)NGRAPH * 32 * 4;
  hipMemsetAsync(bcur, 0, zlen, stream);

  // binned CSR: hist+scatter (+W1/W2 prep folded in); chunk=2048 for parallelism
  const int nbin = (Etot + CH - 1) / CH;
  k_bin<<<nbin + 80, 256, 0, stream>>>(ei, W1, W2, Wt1, Wt2, E, Etot, NB, nbin, bcur, bbuf);

  // build ‖ gemm1 (independent): blocks [0,NB) build CSR, rest run GEMM1+att1
  const int ngemm1 = (N + 63) / 64;
  k_bg<<<NB + ngemm1, 256, 0, stream>>>(bbuf, bcur, NB, N, offs, ssrc,
                                        x, Wt1, nw, as1w, ad1w, hb1, asrc1, adst1);

  // fused: layer-1 aggregation + layer-2 GEMM (MFMA) + att2 -> packed rec2
  k_aggr1<<<(N + 3) / 4, 256, 0, stream>>>(offs, ssrc, hb1, asrc1, adst1, b1,
                                           Wt2, as2w, ad2w, rec2, adst2, N);

  // layer-2 aggregation + in-kernel pooling
  k_aggr2<<<(N + 3) / 4, 256, 0, stream>>>(offs, ssrc, rec2, adst2, b2, batch, gsum, N);

  // pooled mean + fc (tiny)
  k_fc<<<NGRAPH, 64, 0, stream>>>(gsum, batch, fcW, fcb, out, N);
}

// Round 9
// 299.489 us; speedup vs baseline: 1.1787x; 1.0207x over previous
//
#include <hip/hip_runtime.h>
#include <cstdint>

#define NGRAPH 128
#define NEG 0.2f
#define NB_MAX 512      // scan table capacity (buckets); N=100K @BSZ=512 -> 196 buckets
#define BSH 9           // bucket shift
#define BSZ 512         // bucket size (512 -> full-line scatter bursts in k_bin)
#define CAP 16384       // bbuf slots per bucket (expected max ~9600)
#define RC  6144        // k_bg LDS record cache (24KB)
#define CH  4096        // k_bin chunk size

typedef unsigned int uint;
typedef unsigned short ushort;
typedef unsigned char uchar;
typedef __attribute__((ext_vector_type(8))) short bf16x8;
typedef __attribute__((ext_vector_type(4))) float f32x4;
typedef __attribute__((ext_vector_type(2))) float f32x2;

union U4B { uint4 u; bf16x8 v; };

__device__ __forceinline__ ushort f2bf(float f) {
  uint u = __float_as_uint(f);
  uint r = (u + 0x7FFF + ((u >> 16) & 1)) >> 16;   // RNE
  return (ushort)r;
}

// hardware packed bf16 convert (RNE, bit-identical to f2bf) — 1 instr for 2 ch
__device__ __forceinline__ uint cvtpkbf16(float lo, float hi) {
  uint r;
  asm("v_cvt_pk_bf16_f32 %0, %1, %2" : "=v"(r) : "v"(lo), "v"(hi));
  return r;
}

// packed dual f32 FMA: acc = f * w + acc (VOP3P, 1 instr for 2 ch)
__device__ __forceinline__ void pkfma(f32x2& acc, f32x2 f, f32x2 w) {
  asm("v_pk_fma_f32 %0, %1, %2, %0" : "+v"(acc) : "v"(f), "v"(w));
}

__device__ __forceinline__ float bperm_f(int addr, float v) {
  return __int_as_float(__builtin_amdgcn_ds_bpermute(addr, __float_as_int(v)));
}
__device__ __forceinline__ int bperm_i(int addr, int v) {
  return __builtin_amdgcn_ds_bpermute(addr, v);
}

__device__ __forceinline__ int wave_incl_scan_i(int v) {
  int lane = threadIdx.x & 63;
#pragma unroll
  for (int off = 1; off < 64; off <<= 1) {
    int u = __shfl_up(v, off, 64);
    if (lane >= off) v += u;
  }
  return v;
}

// ---------------- k_bin: per-block LDS hist -> bucket alloc -> scatter; + W1/W2 prep ----------------
// pass 1 caches the chunk's packed records in LDS; pass 2 scatters from LDS (no ei re-read).
// BSZ=512 -> ~21 records per bucket region per chunk = ~84B bursts (full line).
__global__ void k_bin(const int* __restrict__ ei,
                      const float* __restrict__ W1, const float* __restrict__ W2,
                      ushort* __restrict__ Wt1, ushort* __restrict__ Wt2,
                      int E, int Etot, int NB, int nbin,
                      int* __restrict__ bcur, uint* __restrict__ bbuf) {
  if (blockIdx.x >= (uint)nbin) {
    int t2 = (blockIdx.x - nbin) * 256 + threadIdx.x;
    if (t2 < 16384) {
      int n = t2 >> 7, k = t2 & 127;
      Wt1[t2] = f2bf(W1[k * 128 + n]);
    } else {
      int u = t2 - 16384;
      int n = u >> 7, k = u & 127;
      Wt2[u] = f2bf(W2[k * 32 + n]);
    }
    return;
  }
  __shared__ int h[NB_MAX];
  __shared__ int baseo[NB_MAX];
  __shared__ uint crec[CH];     // packed (d_local<<17)|s
  __shared__ uchar cbkt[CH];    // bucket id (<=196 fits u8)
  int t = threadIdx.x;
  for (int b = t; b < NB; b += 256) h[b] = 0;
  __syncthreads();
  int cbase = blockIdx.x * CH;
  int cend = min(cbase + CH, Etot);
  int nch = cend - cbase;
  for (int i = t; i < nch; i += 256) {
    int e = cbase + i;
    int s, d;
    if (e < E) {
      s = __builtin_nontemporal_load(&ei[e]);
      d = __builtin_nontemporal_load(&ei[E + e]);
    } else { s = e - E; d = s; }
    int b = d >> BSH;
    crec[i] = ((uint)(d & (BSZ - 1)) << 17) | (uint)s;
    cbkt[i] = (uchar)b;
    atomicAdd(&h[b], 1);
  }
  __syncthreads();
  for (int b = t; b < NB; b += 256) {
    int c = h[b];
    baseo[b] = c ? atomicAdd(&bcur[b], c) : 0;
    h[b] = 0;
  }
  __syncthreads();
  for (int i = t; i < nch; i += 256) {
    int b = cbkt[i];
    int r = atomicAdd(&h[b], 1);
    bbuf[(size_t)b * CAP + baseo[b] + r] = crec[i];
  }
}

// ---------------- k_bg: blocks [0,NB) = CSR build; blocks [NB,..) = GEMM1+att1 ----------------
// CSR half: 512-node buckets; each thread owns 2 nodes in the degree scan.
// rcache covers pass-2 reads for the first RC records of the bucket.
__global__ void k_bg(const uint* __restrict__ bbuf, const int* __restrict__ bcur,
                     int NB, int N, int* __restrict__ offs, int* __restrict__ ssrc,
                     const float* __restrict__ x, const ushort* __restrict__ Wt,
                     const float* __restrict__ nw, const float* __restrict__ att_s,
                     const float* __restrict__ att_d, uchar* __restrict__ hb1,
                     float* __restrict__ asrc, float* __restrict__ adst) {
  __shared__ int sst[NB_MAX + 1];
  __shared__ int wsum2[4];
  __shared__ int deg[BSZ];
  __shared__ uint rcache[RC];
  if (blockIdx.x < (uint)NB) {
    int t = threadIdx.x, lane = t & 63, wid = t >> 6;
    int v0 = (2 * t < NB) ? bcur[2 * t] : 0;
    int v1 = (2 * t + 1 < NB) ? bcur[2 * t + 1] : 0;
    int s = v0 + v1;
    int sv = wave_incl_scan_i(s);
    if (lane == 63) wsum2[wid] = sv;
    deg[t] = 0;
    deg[t + 256] = 0;
    __syncthreads();
    if (t == 0) {
      int r = 0;
#pragma unroll
      for (int k = 0; k < 4; k++) { int x2 = wsum2[k]; wsum2[k] = r; r += x2; }
    }
    __syncthreads();
    int excl = wsum2[wid] + sv - s;
    sst[2 * t] = excl;
    sst[2 * t + 1] = excl + v0;
    if (t == 255) sst[512] = excl + v0 + v1;
    __syncthreads();
    int b = blockIdx.x;
    int ebeg = sst[b], eend = sst[b + 1];
    int cnt = eend - ebeg;
    const uint* brow = bbuf + (size_t)b * CAP;
    for (int i = t; i < cnt; i += 256) {
      uint rec = brow[i];
      if (i < RC) rcache[i] = rec;
      atomicAdd(&deg[rec >> 17], 1);
    }
    __syncthreads();
    // per-node scan: thread t owns nodes 2t, 2t+1 within the bucket
    int u0 = deg[2 * t], u1 = deg[2 * t + 1];
    int s2 = u0 + u1;
    int sv2 = wave_incl_scan_i(s2);
    if (lane == 63) wsum2[wid] = sv2;
    __syncthreads();
    if (t == 0) {
      int r = 0;
#pragma unroll
      for (int k = 0; k < 4; k++) { int x2 = wsum2[k]; wsum2[k] = r; r += x2; }
    }
    __syncthreads();
    int excl2 = wsum2[wid] + sv2 - s2;
    int node0 = (b << BSH) + 2 * t;
    if (node0 < N)     offs[node0]     = ebeg + excl2;
    if (node0 + 1 < N) offs[node0 + 1] = ebeg + excl2 + u0;
    if (b == 0 && t == 0) offs[N] = sst[512];
    __syncthreads();
    deg[2 * t]     = excl2;          // reuse deg as scatter cursors
    deg[2 * t + 1] = excl2 + u0;
    __syncthreads();
    for (int i = t; i < cnt; i += 256) {
      uint rec = (i < RC) ? rcache[i] : brow[i];
      int r = atomicAdd(&deg[rec >> 17], 1);
      ssrc[ebeg + r] = (int)(rec & 0x1FFFF);
    }
    return;
  }
  // ---- gemm1 path (operand-swapped MFMA: D[channel][node]) ----
  int bid = blockIdx.x - NB;
  int wv = threadIdx.x >> 6, l = threadIdx.x & 63;
  int lg = l >> 4, lr = l & 15;
  int row0 = bid * 64 + wv * 16;
  int node = row0 + lr;
  bool valid = node < N;
  float sc = valid ? nw[node] : 0.f;
  bf16x8 xfr[4];
  const float* xr = x + (size_t)node * 128;
#pragma unroll
  for (int kc = 0; kc < 4; kc++) {
    float v[8];
    if (valid) {
      f32x4 q0 = __builtin_nontemporal_load(reinterpret_cast<const f32x4*>(xr + kc * 32 + lg * 8));
      f32x4 q1 = __builtin_nontemporal_load(reinterpret_cast<const f32x4*>(xr + kc * 32 + lg * 8 + 4));
      v[0] = q0[0]; v[1] = q0[1]; v[2] = q0[2]; v[3] = q0[3];
      v[4] = q1[0]; v[5] = q1[1]; v[6] = q1[2]; v[7] = q1[3];
    } else {
#pragma unroll
      for (int j = 0; j < 8; j++) v[j] = 0.f;
    }
    U4B a;
    a.u.x = cvtpkbf16(v[0] * sc, v[1] * sc);
    a.u.y = cvtpkbf16(v[2] * sc, v[3] * sc);
    a.u.z = cvtpkbf16(v[4] * sc, v[5] * sc);
    a.u.w = cvtpkbf16(v[6] * sc, v[7] * sc);
    xfr[kc] = a.v;
  }
  float pS[4] = {}, pD[4] = {};
#pragma unroll
  for (int ct = 0; ct < 8; ct++) {
    f32x4 acc = {0.f, 0.f, 0.f, 0.f};
    const ushort* wrow = Wt + (size_t)(ct * 16 + lr) * 128;
#pragma unroll
    for (int kc = 0; kc < 4; kc++) {
      U4B bfr;
      bfr.u = *reinterpret_cast<const uint4*>(wrow + kc * 32 + lg * 8);
      acc = __builtin_amdgcn_mfma_f32_16x16x32_bf16(bfr.v, xfr[kc], acc, 0, 0, 0);
    }
    int c0 = ct * 16 + lg * 4;
    if (valid) {
      uint u8 = (uint)__builtin_amdgcn_cvt_pk_fp8_f32(acc[0], acc[1], 0, false);
      u8 = (uint)__builtin_amdgcn_cvt_pk_fp8_f32(acc[2], acc[3], u8, true);
      *reinterpret_cast<uint*>(hb1 + (size_t)node * 128 + c0) = u8;
    }
    float4 as4 = *reinterpret_cast<const float4*>(att_s + c0);
    float4 ad4 = *reinterpret_cast<const float4*>(att_d + c0);
    int h = ct >> 1;
    pS[h] += acc[0] * as4.x + acc[1] * as4.y + acc[2] * as4.z + acc[3] * as4.w;
    pD[h] += acc[0] * ad4.x + acc[1] * ad4.y + acc[2] * ad4.z + acc[3] * ad4.w;
  }
#pragma unroll
  for (int off = 16; off < 64; off <<= 1) {
#pragma unroll
    for (int h = 0; h < 4; h++) {
      pS[h] += __shfl_xor(pS[h], off, 64);
      pD[h] += __shfl_xor(pD[h], off, 64);
    }
  }
  if (lg == 0 && valid) {
    *reinterpret_cast<float4*>(asrc + node * 4) = make_float4(pS[0], pS[1], pS[2], pS[3]);
    *reinterpret_cast<float4*>(adst + node * 4) = make_float4(pD[0], pD[1], pD[2], pD[3]);
  }
}

// ---- fused layer-1 aggregation + layer-2 GEMM (MFMA, wave-0 tail) + att2 ----
// chunked schedule: phase A computes 32 edge-weights wave-wide (lane = edge x head),
// phase B bpermutes s/w and keeps 4 row loads in flight.
// layer-2 output goes into 64-B packed records: [32B fp8 row | 4B asrc2 | pad].
__global__ void k_aggr1(const int* __restrict__ offs, const int* __restrict__ ssrc,
                        const uchar* __restrict__ hb, const float* __restrict__ asrc,
                        const float* __restrict__ adst, const float* __restrict__ bias,
                        const ushort* __restrict__ Wt2, const float* __restrict__ as2,
                        const float* __restrict__ ad2, uchar* __restrict__ rec2,
                        float* __restrict__ adst2, int N) {
  __shared__ ushort rowl[4][136];    // bf16 out1 rows, +8 pad
  int tid = threadIdx.x;
  int wv = tid >> 6, l = tid & 63;
  int d = blockIdx.x * 4 + wv;
  int dc = min(d, N - 1);
  int slot = l >> 3;       // 0..7 edge slot (phase B)
  int cb = l & 7;          // channel block: ch cb*16 .. +15
  int h = cb >> 1;         // head of this lane's channels
  int hq = l & 3;          // phase-A head
  int eidx = l >> 2;       // phase-A edge-in-chunk 0..15
  float adq = adst[dc * 4 + hq];
  int beg = offs[dc], end = offs[dc + 1];
  int endm1 = end - 1;
  const uchar* hbc = hb + cb * 16;
  int bp0 = (slot * 4 + h) << 2;   // bpermute byte addr, edge slot (it even)
  int bp1 = bp0 + 128;             // +32 lanes (it odd)
  f32x2 a2[8] = {};
  float dsp = 0.f;
  auto ACC = [&](uint4 p, float w) {
    f32x2 wp = {w, w};
    f32x2 f;
    f = __builtin_amdgcn_cvt_pk_f32_fp8(p.x, false); pkfma(a2[0], f, wp);
    f = __builtin_amdgcn_cvt_pk_f32_fp8(p.x, true);  pkfma(a2[1], f, wp);
    f = __builtin_amdgcn_cvt_pk_f32_fp8(p.y, false); pkfma(a2[2], f, wp);
    f = __builtin_amdgcn_cvt_pk_f32_fp8(p.y, true);  pkfma(a2[3], f, wp);
    f = __builtin_amdgcn_cvt_pk_f32_fp8(p.z, false); pkfma(a2[4], f, wp);
    f = __builtin_amdgcn_cvt_pk_f32_fp8(p.z, true);  pkfma(a2[5], f, wp);
    f = __builtin_amdgcn_cvt_pk_f32_fp8(p.w, false); pkfma(a2[6], f, wp);
    f = __builtin_amdgcn_cvt_pk_f32_fp8(p.w, true);  pkfma(a2[7], f, wp);
  };
  for (int base = beg; base < end; base += 32) {
    // ---- phase A: 32 edge-weights, lane = (edge 0..15) x (head 0..3) ----
    int eA = base + eidx;
    int eB = eA + 16;
    int sA = ssrc[min(eA, endm1)];
    int sB = ssrc[min(eB, endm1)];
    // s redistribution does not depend on exp -> issue row loads early
    int s0 = bperm_i(bp0, sA);
    int s1 = bperm_i(bp1, sA);
    int s2 = bperm_i(bp0, sB);
    int s3 = bperm_i(bp1, sB);
    int rem = end - base;
    uint4 p0, p1, p2, p3;
    p0 = *reinterpret_cast<const uint4*>(hbc + (size_t)s0 * 128);
    if (rem > 8)  p1 = *reinterpret_cast<const uint4*>(hbc + (size_t)s1 * 128);
    if (rem > 16) p2 = *reinterpret_cast<const uint4*>(hbc + (size_t)s2 * 128);
    if (rem > 24) p3 = *reinterpret_cast<const uint4*>(hbc + (size_t)s3 * 128);
    float aA = asrc[sA * 4 + hq] + adq;     // coalesced 16B across 4 head lanes
    float aB = asrc[sB * 4 + hq] + adq;
    aA = fmaxf(aA, aA * NEG);
    aB = fmaxf(aB, aB * NEG);
    float wA = (eA < end) ? __expf(aA) : 0.f;
    float wB = (eB < end) ? __expf(aB) : 0.f;
    dsp += wA + wB;
    float w0 = bperm_f(bp0, wA);
    float w1 = bperm_f(bp1, wA);
    float w2 = bperm_f(bp0, wB);
    float w3 = bperm_f(bp1, wB);
    // ---- phase B: consume (guards are wave-uniform) ----
    ACC(p0, w0);
    if (rem > 8)  ACC(p1, w1);
    if (rem > 16) ACC(p2, w2);
    if (rem > 24) ACC(p3, w3);
  }
  // softmax denominator: sum over stride-4 lane groups (per head), then broadcast
  dsp += __shfl_xor(dsp, 4, 64);
  dsp += __shfl_xor(dsp, 8, 64);
  dsp += __shfl_xor(dsp, 16, 64);
  dsp += __shfl_xor(dsp, 32, 64);
  float ds = bperm_f(h << 2, dsp);
  int b3 = (l >> 3) & 1, b4 = (l >> 4) & 1, b5 = (l >> 5) & 1;
  float t8[8];
#pragma unroll
  for (int r = 0; r < 8; r++) {
    float av = a2[r >> 1][r & 1];
    float bv = a2[(r + 8) >> 1][r & 1];
    float send = b3 ? av : bv;
    float recv = __shfl_xor(send, 8, 64);
    t8[r] = (b3 ? bv : av) + recv;
  }
  float t4[4];
#pragma unroll
  for (int r = 0; r < 4; r++) {
    float send = b4 ? t8[r] : t8[r + 4];
    float recv = __shfl_xor(send, 16, 64);
    t4[r] = (b4 ? t8[r + 4] : t8[r]) + recv;
  }
  float t2[2];
#pragma unroll
  for (int r = 0; r < 2; r++) {
    float send = b5 ? t4[r] : t4[r + 2];
    float recv = __shfl_xor(send, 32, 64);
    t2[r] = (b5 ? t4[r + 2] : t4[r]) + recv;
  }
  float inv = __builtin_amdgcn_rcpf(ds > 0.f ? ds : 1.f);
  int c0 = cb * 16 + b3 * 8 + b4 * 4 + b5 * 2;
  float2 bi = *reinterpret_cast<const float2*>(bias + c0);
  float r0 = fmaf(t2[0], inv, bi.x);
  float r1 = fmaf(t2[1], inv, bi.y);
  r0 = r0 > 0.f ? r0 : __expf(r0) - 1.f;   // elu via exp (abs err ~1e-7)
  r1 = r1 > 0.f ? r1 : __expf(r1) - 1.f;
  *reinterpret_cast<uint*>(&rowl[wv][c0]) = cvtpkbf16(r0, r1);
  __syncthreads();
  if (wv != 0) return;
  // ---- gemm2 + att2 on the block's 4 rows (wave 0 only) ----
  int lg = l >> 4, lr = l & 15;
  int rsel = lr & 3;
  bf16x8 bfrag[4];
#pragma unroll
  for (int kc = 0; kc < 4; kc++) {
    U4B bb;
    bb.u = *reinterpret_cast<const uint4*>(&rowl[rsel][kc * 32 + lg * 8]);
    bfrag[kc] = bb.v;
  }
  int dd = blockIdx.x * 4 + lr;      // valid only for lr<4
  bool vs = (lr < 4) && (dd < N);
  float pS = 0.f, pD = 0.f;
#pragma unroll
  for (int ct = 0; ct < 2; ct++) {
    f32x4 acc = {0.f, 0.f, 0.f, 0.f};
    const ushort* wrow = Wt2 + (size_t)(ct * 16 + lr) * 128;
#pragma unroll
    for (int kc = 0; kc < 4; kc++) {
      U4B bfr;
      bfr.u = *reinterpret_cast<const uint4*>(wrow + kc * 32 + lg * 8);
      acc = __builtin_amdgcn_mfma_f32_16x16x32_bf16(bfr.v, bfrag[kc], acc, 0, 0, 0);
    }
    int cg = ct * 16 + lg * 4;
    if (vs) {
      uint u8 = (uint)__builtin_amdgcn_cvt_pk_fp8_f32(acc[0], acc[1], 0, false);
      u8 = (uint)__builtin_amdgcn_cvt_pk_fp8_f32(acc[2], acc[3], u8, true);
      *reinterpret_cast<uint*>(rec2 + (size_t)dd * 64 + cg) = u8;
    }
    float4 as4 = *reinterpret_cast<const float4*>(as2 + cg);
    float4 ad4 = *reinterpret_cast<const float4*>(ad2 + cg);
    pS += acc[0] * as4.x + acc[1] * as4.y + acc[2] * as4.z + acc[3] * as4.w;
    pD += acc[0] * ad4.x + acc[1] * ad4.y + acc[2] * ad4.z + acc[3] * ad4.w;
  }
  pS += __shfl_xor(pS, 16, 64);
  pS += __shfl_xor(pS, 32, 64);
  pD += __shfl_xor(pD, 16, 64);
  pD += __shfl_xor(pD, 32, 64);
  if (vs && lg == 0) {
    *reinterpret_cast<float*>(rec2 + (size_t)dd * 64 + 32) = pS;
    adst2[dd] = pD;
  }
}

// ---- layer-2 aggregation + in-kernel graph pooling ----
// 64-B packed records: phase-A asrc load warms the line phase-B's row load hits.
// Per-block LDS pooling (batch sorted -> <=4 graph slots), then atomics into gsum.
__global__ void k_aggr2(const int* __restrict__ offs, const int* __restrict__ ssrc,
                        const uchar* __restrict__ rec, const float* __restrict__ adst,
                        const float* __restrict__ bias, const int* __restrict__ batch,
                        float* __restrict__ gsum, int N) {
  __shared__ float sblk[4][32];
  int tid = threadIdx.x;
  int wid = tid >> 6, l = tid & 63;
  if (tid < 128) sblk[tid >> 5][tid & 31] = 0.f;
  __syncthreads();
  int d = blockIdx.x * 4 + wid;
  bool valid = d < N;
  int dc = valid ? d : N - 1;
  int slot = l >> 2;       // 0..15 edge slot (phase B)
  int k = l & 3;           // channel block: ch k*8 .. +7
  float ad = adst[dc];
  int beg = offs[dc];
  int end = valid ? offs[dc + 1] : beg;
  int endm1 = end - 1;
  const uchar* rk = rec + k * 8;
  int bq0 = slot << 2;
  int bq1 = (slot + 16) << 2;
  int bq2 = (slot + 32) << 2;
  int bq3 = (slot + 48) << 2;
  f32x2 a2[4] = {};
  float dsp = 0.f;
  auto ACC2 = [&](uint2 p, float w) {
    f32x2 wp = {w, w};
    f32x2 f;
    f = __builtin_amdgcn_cvt_pk_f32_fp8(p.x, false); pkfma(a2[0], f, wp);
    f = __builtin_amdgcn_cvt_pk_f32_fp8(p.x, true);  pkfma(a2[1], f, wp);
    f = __builtin_amdgcn_cvt_pk_f32_fp8(p.y, false); pkfma(a2[2], f, wp);
    f = __builtin_amdgcn_cvt_pk_f32_fp8(p.y, true);  pkfma(a2[3], f, wp);
  };
  for (int base = beg; base < end; base += 64) {
    // phase A: 64 edge-weights, one per lane; asrc packed at row+32 warms the line
    int e = base + l;
    int sL = ssrc[min(e, endm1)];
    int s0 = bperm_i(bq0, sL);
    int s1 = bperm_i(bq1, sL);
    int s2 = bperm_i(bq2, sL);
    int s3 = bperm_i(bq3, sL);
    int rem = end - base;
    float av = *reinterpret_cast<const float*>(rec + (size_t)sL * 64 + 32);
    uint2 p0, p1, p2, p3;
    p0 = *reinterpret_cast<const uint2*>(rk + (size_t)s0 * 64);
    if (rem > 16) p1 = *reinterpret_cast<const uint2*>(rk + (size_t)s1 * 64);
    if (rem > 32) p2 = *reinterpret_cast<const uint2*>(rk + (size_t)s2 * 64);
    if (rem > 48) p3 = *reinterpret_cast<const uint2*>(rk + (size_t)s3 * 64);
    float xv = av + ad;
    xv = fmaxf(xv, xv * NEG);
    float wL = (e < end) ? __expf(xv) : 0.f;
    dsp += wL;
    float w0 = bperm_f(bq0, wL);
    float w1 = bperm_f(bq1, wL);
    float w2 = bperm_f(bq2, wL);
    float w3 = bperm_f(bq3, wL);
    ACC2(p0, w0);
    if (rem > 16) ACC2(p1, w1);
    if (rem > 32) ACC2(p2, w2);
    if (rem > 48) ACC2(p3, w3);
  }
  dsp += __shfl_xor(dsp, 1, 64);
  dsp += __shfl_xor(dsp, 2, 64);
  dsp += __shfl_xor(dsp, 4, 64);
  dsp += __shfl_xor(dsp, 8, 64);
  dsp += __shfl_xor(dsp, 16, 64);
  dsp += __shfl_xor(dsp, 32, 64);
  int b2 = (l >> 2) & 1, b3 = (l >> 3) & 1, b4 = (l >> 4) & 1;
  float t4[4];
#pragma unroll
  for (int r = 0; r < 4; r++) {
    float av = a2[r >> 1][r & 1];
    float bv = a2[(r + 4) >> 1][r & 1];
    float send = b2 ? av : bv;
    float recv = __shfl_xor(send, 4, 64);
    t4[r] = (b2 ? bv : av) + recv;
  }
  float t2[2];
#pragma unroll
  for (int r = 0; r < 2; r++) {
    float send = b3 ? t4[r] : t4[r + 2];
    float recv = __shfl_xor(send, 8, 64);
    t2[r] = (b3 ? t4[r + 2] : t4[r]) + recv;
  }
  float send = b4 ? t2[0] : t2[1];
  float recv = __shfl_xor(send, 16, 64);
  float t1 = (b4 ? t2[1] : t2[0]) + recv;
  t1 += __shfl_xor(t1, 32, 64);
  int gfirst = batch[blockIdx.x * 4];     // first node of block always < N
  if (l < 32 && valid) {
    int c = k * 8 + b2 * 4 + b3 * 2 + b4;
    float inv = __builtin_amdgcn_rcpf(dsp > 0.f ? dsp : 1.f);
    float r = fmaf(t1, inv, bias[c]);
    r = r > 0.f ? r : __expf(r) - 1.f;
    int g = batch[dc];
    int sl = g - gfirst;
    if (sl < 4) atomicAdd(&sblk[sl][c], r);
    else atomicAdd(&gsum[g * 32 + c], r);   // rare: >4 graphs in one block
  }
  __syncthreads();
  if (tid < 128) {
    int sl = tid >> 5, c = tid & 31;
    float v = sblk[sl][c];
    int gg = gfirst + sl;
    if (v != 0.f && gg < NGRAPH) atomicAdd(&gsum[gg * 32 + c], v);
  }
}

// ---------------- k_fc: pooled mean (from gsum + binary-search counts) + FC ----------------
__global__ void k_fc(const float* __restrict__ gsum, const int* __restrict__ batch,
                     const float* __restrict__ fcW, const float* __restrict__ fcb,
                     float* __restrict__ out, int N) {
  int g = blockIdx.x;
  int l = threadIdx.x;
  int lo = 0, hi = N;
  while (lo < hi) { int mid = (lo + hi) >> 1; if (batch[mid] < g) lo = mid + 1; else hi = mid; }
  int beg = lo;
  hi = N;
  while (lo < hi) { int mid = (lo + hi) >> 1; if (batch[mid] < g + 1) lo = mid + 1; else hi = mid; }
  int end = lo;
  float inv = 1.f / fmaxf((float)(end - beg), 1.f);
  __shared__ float pooled[32];
  if (l < 32) pooled[l] = gsum[g * 32 + l] * inv;
  __syncthreads();
  if (l < 16) {
    float r = fcb[l];
#pragma unroll
    for (int cc = 0; cc < 32; cc++) r += pooled[cc] * fcW[cc * 16 + l];
    out[g * 16 + l] = r;
  }
}

// ---------------- host launch ----------------
extern "C" void kernel_launch(void* const* d_in, const int* in_sizes, int n_in,
                              void* d_out, int out_size, void* d_ws, size_t ws_size,
                              hipStream_t stream) {
  const float* x     = (const float*)d_in[0];
  const int*   ei    = (const int*)d_in[1];
  const int*   batch = (const int*)d_in[2];
  const float* nw    = (const float*)d_in[3];
  const float* W1    = (const float*)d_in[4];
  const float* as1w  = (const float*)d_in[5];
  const float* ad1w  = (const float*)d_in[6];
  const float* b1    = (const float*)d_in[7];
  const float* W2    = (const float*)d_in[8];
  const float* as2w  = (const float*)d_in[9];
  const float* ad2w  = (const float*)d_in[10];
  const float* b2    = (const float*)d_in[11];
  const float* fcW   = (const float*)d_in[12];
  const float* fcb   = (const float*)d_in[13];
  float* out = (float*)d_out;

  const int N = in_sizes[0] / 128;
  const int E = in_sizes[1] / 2;
  const int Etot = E + N;
  const int NB = (N + BSZ - 1) >> BSH;

  char* w = (char*)d_ws;
  size_t ofs = 0;
  auto alloc = [&](size_t bytes) {
    char* p = w + ofs;
    ofs += (bytes + 255) & ~(size_t)255;
    return p;
  };
  uchar*  hb1    = (uchar*)alloc((size_t)N * 128);        // fp8 layer-1 features
  uchar*  rec2   = (uchar*)alloc((size_t)N * 64);         // [32B fp8 row | 4B asrc2 | pad]
  float*  asrc1  = (float*)alloc((size_t)N * 4 * 4);
  float*  adst1  = (float*)alloc((size_t)N * 4 * 4);
  float*  adst2  = (float*)alloc((size_t)N * 4);
  ushort* Wt1    = (ushort*)alloc(16384 * 2);
  ushort* Wt2    = (ushort*)alloc(4096 * 2);
  int*    bcur   = (int*)alloc((size_t)NB * 4);
  float*  gsum   = (float*)alloc((size_t)NGRAPH * 32 * 4);
  int*    offs   = (int*)alloc((size_t)(N + 1) * 4);
  uint*   bbuf   = (uint*)alloc((size_t)NB * CAP * 4);
  int*    ssrc   = (int*)alloc((size_t)Etot * 4);

  // one memset zeroes bcur + gsum (allocated adjacently)
  size_t zlen = (size_t)((char*)gsum - (char*)bcur) + (size_t)NGRAPH * 32 * 4;
  hipMemsetAsync(bcur, 0, zlen, stream);

  // binned CSR: hist+scatter (+W1/W2 prep folded in)
  const int nbin = (Etot + CH - 1) / CH;
  k_bin<<<nbin + 80, 256, 0, stream>>>(ei, W1, W2, Wt1, Wt2, E, Etot, NB, nbin, bcur, bbuf);

  // build ‖ gemm1 (independent): blocks [0,NB) build CSR, rest run GEMM1+att1
  const int ngemm1 = (N + 63) / 64;
  k_bg<<<NB + ngemm1, 256, 0, stream>>>(bbuf, bcur, NB, N, offs, ssrc,
                                        x, Wt1, nw, as1w, ad1w, hb1, asrc1, adst1);

  // fused: layer-1 aggregation + layer-2 GEMM (MFMA) + att2 -> packed rec2
  k_aggr1<<<(N + 3) / 4, 256, 0, stream>>>(offs, ssrc, hb1, asrc1, adst1, b1,
                                           Wt2, as2w, ad2w, rec2, adst2, N);

  // layer-2 aggregation + in-kernel pooling
  k_aggr2<<<(N + 3) / 4, 256, 0, stream>>>(offs, ssrc, rec2, adst2, b2, batch, gsum, N);

  // pooled mean + fc (tiny)
  k_fc<<<NGRAPH, 64, 0, stream>>>(gsum, batch, fcW, fcb, out, N);
}

// Round 10
// 292.228 us; speedup vs baseline: 1.2080x; 1.0248x over previous
//
#include <hip/hip_runtime.h>
#include <cstdint>

#define NGRAPH 128
#define NEG 0.2f
#define NB_MAX 512      // buckets of 256 dst nodes; N=100K -> 391 buckets
#define BSH 8           // bucket shift
#define BSZ 256         // bucket size
#define CAP 8192        // bbuf slots per bucket (expected max ~4800)
#define RC  6144        // k_bg LDS record cache (24KB)
#define CH  4096        // k_bin chunk size

typedef unsigned int uint;
typedef unsigned short ushort;
typedef unsigned char uchar;
typedef __attribute__((ext_vector_type(8))) short bf16x8;
typedef __attribute__((ext_vector_type(4))) float f32x4;
typedef __attribute__((ext_vector_type(2))) float f32x2;

union U4B { uint4 u; bf16x8 v; };

__device__ __forceinline__ ushort f2bf(float f) {
  uint u = __float_as_uint(f);
  uint r = (u + 0x7FFF + ((u >> 16) & 1)) >> 16;   // RNE
  return (ushort)r;
}

// hardware packed bf16 convert (RNE, bit-identical to f2bf) — 1 instr for 2 ch
__device__ __forceinline__ uint cvtpkbf16(float lo, float hi) {
  uint r;
  asm("v_cvt_pk_bf16_f32 %0, %1, %2" : "=v"(r) : "v"(lo), "v"(hi));
  return r;
}

// packed dual f32 FMA: acc = f * w + acc (VOP3P, 1 instr for 2 ch)
__device__ __forceinline__ void pkfma(f32x2& acc, f32x2 f, f32x2 w) {
  asm("v_pk_fma_f32 %0, %1, %2, %0" : "+v"(acc) : "v"(f), "v"(w));
}

__device__ __forceinline__ float bperm_f(int addr, float v) {
  return __int_as_float(__builtin_amdgcn_ds_bpermute(addr, __float_as_int(v)));
}
__device__ __forceinline__ int bperm_i(int addr, int v) {
  return __builtin_amdgcn_ds_bpermute(addr, v);
}

__device__ __forceinline__ int wave_incl_scan_i(int v) {
  int lane = threadIdx.x & 63;
#pragma unroll
  for (int off = 1; off < 64; off <<= 1) {
    int u = __shfl_up(v, off, 64);
    if (lane >= off) v += u;
  }
  return v;
}

// ---------------- k_bin: LDS hist -> bucket alloc -> LDS counting sort -> COALESCED scatter ----------------
// pass 1 caches records in LDS; pass 2 sorts by bucket inside LDS; pass 3 writes
// bucket-sorted runs linearly (consecutive lanes -> consecutive addresses per run).
__global__ void k_bin(const int* __restrict__ ei,
                      const float* __restrict__ W1, const float* __restrict__ W2,
                      ushort* __restrict__ Wt1, ushort* __restrict__ Wt2,
                      int E, int Etot, int NB, int nbin,
                      int* __restrict__ bcur, uint* __restrict__ bbuf) {
  if (blockIdx.x >= (uint)nbin) {
    int t2 = (blockIdx.x - nbin) * 256 + threadIdx.x;
    if (t2 < 16384) {
      int n = t2 >> 7, k = t2 & 127;
      Wt1[t2] = f2bf(W1[k * 128 + n]);
    } else {
      int u = t2 - 16384;
      int n = u >> 7, k = u & 127;
      Wt2[u] = f2bf(W2[k * 32 + n]);
    }
    return;
  }
  __shared__ int h[NB_MAX];        // counts, then pass-2 cursors
  __shared__ int baseo[NB_MAX];    // global base per bucket (this chunk)
  __shared__ int lofs[NB_MAX];     // local sorted-offset per bucket
  __shared__ int wsc[4];
  __shared__ uint crec[CH];        // packed (d_local<<17)|s, load order
  __shared__ ushort cbkt[CH];      // bucket id, load order
  __shared__ uint srec[CH];        // bucket-sorted records
  __shared__ ushort sbkt[CH];      // bucket id, sorted order
  int t = threadIdx.x, lane = t & 63, wid = t >> 6;
  for (int b = t; b < NB; b += 256) h[b] = 0;
  __syncthreads();
  int cbase = blockIdx.x * CH;
  int cend = min(cbase + CH, Etot);
  int nch = cend - cbase;
  for (int i = t; i < nch; i += 256) {
    int e = cbase + i;
    int s, d;
    if (e < E) { s = ei[e]; d = ei[E + e]; } else { s = e - E; d = s; }
    int b = d >> BSH;
    crec[i] = ((uint)(d & (BSZ - 1)) << 17) | (uint)s;
    cbkt[i] = (ushort)b;
    atomicAdd(&h[b], 1);
  }
  __syncthreads();
  // local exclusive prefix over h[0..NB): thread t owns buckets 2t, 2t+1
  int v0 = (2 * t < NB) ? h[2 * t] : 0;
  int v1 = (2 * t + 1 < NB) ? h[2 * t + 1] : 0;
  int s2 = v0 + v1;
  int sv = wave_incl_scan_i(s2);
  if (lane == 63) wsc[wid] = sv;
  __syncthreads();
  if (t == 0) {
    int r = 0;
#pragma unroll
    for (int k = 0; k < 4; k++) { int x2 = wsc[k]; wsc[k] = r; r += x2; }
  }
  __syncthreads();
  int excl = wsc[wid] + sv - s2;
  if (2 * t < NB)     lofs[2 * t]     = excl;
  if (2 * t + 1 < NB) lofs[2 * t + 1] = excl + v0;
  // global base alloc + reset cursors (h reads by scan all precede via syncs)
  for (int b = t; b < NB; b += 256) {
    int c = h[b];
    baseo[b] = c ? atomicAdd(&bcur[b], c) : 0;
    h[b] = 0;
  }
  __syncthreads();
  // pass 2: counting-sort into srec/sbkt
  for (int i = t; i < nch; i += 256) {
    int b = cbkt[i];
    int r = atomicAdd(&h[b], 1);
    int p = lofs[b] + r;
    srec[p] = crec[i];
    sbkt[p] = (ushort)b;
  }
  __syncthreads();
  // pass 3: coalesced write — per-bucket runs are contiguous in i
  for (int i = t; i < nch; i += 256) {
    int b = sbkt[i];
    bbuf[(size_t)b * CAP + baseo[b] + (i - lofs[b])] = srec[i];
  }
}

// ---------------- k_bg: blocks [0,NB) = CSR build; blocks [NB,..) = GEMM1+att1 ----------------
// CSR half caches bucket records in LDS during the hist pass; scatter pass reads from LDS.
__global__ void k_bg(const uint* __restrict__ bbuf, const int* __restrict__ bcur,
                     int NB, int N, int* __restrict__ offs, int* __restrict__ ssrc,
                     const float* __restrict__ x, const ushort* __restrict__ Wt,
                     const float* __restrict__ nw, const float* __restrict__ att_s,
                     const float* __restrict__ att_d, uchar* __restrict__ hb1,
                     float* __restrict__ asrc, float* __restrict__ adst) {
  __shared__ int sst[NB_MAX + 1];
  __shared__ int wsum2[4];
  __shared__ int deg[BSZ];
  __shared__ uint rcache[RC];
  if (blockIdx.x < (uint)NB) {
    int t = threadIdx.x, lane = t & 63, wid = t >> 6;
    int v0 = (2 * t < NB) ? bcur[2 * t] : 0;
    int v1 = (2 * t + 1 < NB) ? bcur[2 * t + 1] : 0;
    int s = v0 + v1;
    int sv = wave_incl_scan_i(s);
    if (lane == 63) wsum2[wid] = sv;
    deg[t] = 0;
    __syncthreads();
    if (t == 0) {
      int r = 0;
#pragma unroll
      for (int k = 0; k < 4; k++) { int x2 = wsum2[k]; wsum2[k] = r; r += x2; }
    }
    __syncthreads();
    int excl = wsum2[wid] + sv - s;
    sst[2 * t] = excl;
    sst[2 * t + 1] = excl + v0;
    if (t == 255) sst[512] = excl + v0 + v1;
    __syncthreads();
    int b = blockIdx.x;
    int ebeg = sst[b], eend = sst[b + 1];
    int cnt = eend - ebeg;
    const uint* brow = bbuf + (size_t)b * CAP;
    for (int i = t; i < cnt; i += BSZ) {
      uint rec = brow[i];
      if (i < RC) rcache[i] = rec;
      atomicAdd(&deg[rec >> 17], 1);
    }
    __syncthreads();
    int v = deg[t];
    int sv2 = wave_incl_scan_i(v);
    if (lane == 63) wsum2[wid] = sv2;
    __syncthreads();
    if (t == 0) {
      int r = 0;
#pragma unroll
      for (int k = 0; k < 4; k++) { int x2 = wsum2[k]; wsum2[k] = r; r += x2; }
    }
    __syncthreads();
    int excl2 = wsum2[wid] + sv2 - v;
    int node = (b << BSH) + t;
    if (node < N) offs[node] = ebeg + excl2;
    if (b == 0 && t == 0) offs[N] = sst[512];
    __syncthreads();
    deg[t] = excl2;
    __syncthreads();
    for (int i = t; i < cnt; i += BSZ) {
      uint rec = (i < RC) ? rcache[i] : brow[i];
      int r = atomicAdd(&deg[rec >> 17], 1);
      ssrc[ebeg + r] = (int)(rec & 0x1FFFF);
    }
    return;
  }
  // ---- gemm1 path (operand-swapped MFMA: D[channel][node]) ----
  int bid = blockIdx.x - NB;
  int wv = threadIdx.x >> 6, l = threadIdx.x & 63;
  int lg = l >> 4, lr = l & 15;
  int row0 = bid * 64 + wv * 16;
  int node = row0 + lr;
  bool valid = node < N;
  float sc = valid ? nw[node] : 0.f;
  bf16x8 xfr[4];
  const float* xr = x + (size_t)node * 128;
#pragma unroll
  for (int kc = 0; kc < 4; kc++) {
    float v[8];
    if (valid) {
      float4 q0 = *reinterpret_cast<const float4*>(xr + kc * 32 + lg * 8);
      float4 q1 = *reinterpret_cast<const float4*>(xr + kc * 32 + lg * 8 + 4);
      v[0] = q0.x; v[1] = q0.y; v[2] = q0.z; v[3] = q0.w;
      v[4] = q1.x; v[5] = q1.y; v[6] = q1.z; v[7] = q1.w;
    } else {
#pragma unroll
      for (int j = 0; j < 8; j++) v[j] = 0.f;
    }
    U4B a;
    a.u.x = cvtpkbf16(v[0] * sc, v[1] * sc);
    a.u.y = cvtpkbf16(v[2] * sc, v[3] * sc);
    a.u.z = cvtpkbf16(v[4] * sc, v[5] * sc);
    a.u.w = cvtpkbf16(v[6] * sc, v[7] * sc);
    xfr[kc] = a.v;
  }
  float pS[4] = {}, pD[4] = {};
#pragma unroll
  for (int ct = 0; ct < 8; ct++) {
    f32x4 acc = {0.f, 0.f, 0.f, 0.f};
    const ushort* wrow = Wt + (size_t)(ct * 16 + lr) * 128;
#pragma unroll
    for (int kc = 0; kc < 4; kc++) {
      U4B bfr;
      bfr.u = *reinterpret_cast<const uint4*>(wrow + kc * 32 + lg * 8);
      acc = __builtin_amdgcn_mfma_f32_16x16x32_bf16(bfr.v, xfr[kc], acc, 0, 0, 0);
    }
    int c0 = ct * 16 + lg * 4;
    if (valid) {
      uint u8 = (uint)__builtin_amdgcn_cvt_pk_fp8_f32(acc[0], acc[1], 0, false);
      u8 = (uint)__builtin_amdgcn_cvt_pk_fp8_f32(acc[2], acc[3], u8, true);
      *reinterpret_cast<uint*>(hb1 + (size_t)node * 128 + c0) = u8;
    }
    float4 as4 = *reinterpret_cast<const float4*>(att_s + c0);
    float4 ad4 = *reinterpret_cast<const float4*>(att_d + c0);
    int h = ct >> 1;
    pS[h] += acc[0] * as4.x + acc[1] * as4.y + acc[2] * as4.z + acc[3] * as4.w;
    pD[h] += acc[0] * ad4.x + acc[1] * ad4.y + acc[2] * ad4.z + acc[3] * ad4.w;
  }
#pragma unroll
  for (int off = 16; off < 64; off <<= 1) {
#pragma unroll
    for (int h = 0; h < 4; h++) {
      pS[h] += __shfl_xor(pS[h], off, 64);
      pD[h] += __shfl_xor(pD[h], off, 64);
    }
  }
  if (lg == 0 && valid) {
    *reinterpret_cast<float4*>(asrc + node * 4) = make_float4(pS[0], pS[1], pS[2], pS[3]);
    *reinterpret_cast<float4*>(adst + node * 4) = make_float4(pD[0], pD[1], pD[2], pD[3]);
  }
}

// ---- fused layer-1 aggregation + layer-2 GEMM (MFMA, wave-0 tail) + att2 ----
// chunked schedule: phase A computes 32 edge-weights wave-wide (lane = edge x head),
// phase B bpermutes s/w and keeps 4 row loads in flight.
// layer-2 output goes into 64-B packed records: [32B fp8 row | 4B asrc2 | pad].
__global__ void k_aggr1(const int* __restrict__ offs, const int* __restrict__ ssrc,
                        const uchar* __restrict__ hb, const float* __restrict__ asrc,
                        const float* __restrict__ adst, const float* __restrict__ bias,
                        const ushort* __restrict__ Wt2, const float* __restrict__ as2,
                        const float* __restrict__ ad2, uchar* __restrict__ rec2,
                        float* __restrict__ adst2, int N) {
  __shared__ ushort rowl[4][136];    // bf16 out1 rows, +8 pad
  int tid = threadIdx.x;
  int wv = tid >> 6, l = tid & 63;
  int d = blockIdx.x * 4 + wv;
  int dc = min(d, N - 1);
  int slot = l >> 3;       // 0..7 edge slot (phase B)
  int cb = l & 7;          // channel block: ch cb*16 .. +15
  int h = cb >> 1;         // head of this lane's channels
  int hq = l & 3;          // phase-A head
  int eidx = l >> 2;       // phase-A edge-in-chunk 0..15
  float adq = adst[dc * 4 + hq];
  int beg = offs[dc], end = offs[dc + 1];
  int endm1 = end - 1;
  const uchar* hbc = hb + cb * 16;
  int bp0 = (slot * 4 + h) << 2;   // bpermute byte addr, edge slot (it even)
  int bp1 = bp0 + 128;             // +32 lanes (it odd)
  f32x2 a2[8] = {};
  float dsp = 0.f;
  auto ACC = [&](uint4 p, float w) {
    f32x2 wp = {w, w};
    f32x2 f;
    f = __builtin_amdgcn_cvt_pk_f32_fp8(p.x, false); pkfma(a2[0], f, wp);
    f = __builtin_amdgcn_cvt_pk_f32_fp8(p.x, true);  pkfma(a2[1], f, wp);
    f = __builtin_amdgcn_cvt_pk_f32_fp8(p.y, false); pkfma(a2[2], f, wp);
    f = __builtin_amdgcn_cvt_pk_f32_fp8(p.y, true);  pkfma(a2[3], f, wp);
    f = __builtin_amdgcn_cvt_pk_f32_fp8(p.z, false); pkfma(a2[4], f, wp);
    f = __builtin_amdgcn_cvt_pk_f32_fp8(p.z, true);  pkfma(a2[5], f, wp);
    f = __builtin_amdgcn_cvt_pk_f32_fp8(p.w, false); pkfma(a2[6], f, wp);
    f = __builtin_amdgcn_cvt_pk_f32_fp8(p.w, true);  pkfma(a2[7], f, wp);
  };
  for (int base = beg; base < end; base += 32) {
    // ---- phase A: 32 edge-weights, lane = (edge 0..15) x (head 0..3) ----
    int eA = base + eidx;
    int eB = eA + 16;
    int sA = ssrc[min(eA, endm1)];
    int sB = ssrc[min(eB, endm1)];
    // s redistribution does not depend on exp -> issue row loads early
    int s0 = bperm_i(bp0, sA);
    int s1 = bperm_i(bp1, sA);
    int s2 = bperm_i(bp0, sB);
    int s3 = bperm_i(bp1, sB);
    int rem = end - base;
    uint4 p0, p1, p2, p3;
    p0 = *reinterpret_cast<const uint4*>(hbc + (size_t)s0 * 128);
    if (rem > 8)  p1 = *reinterpret_cast<const uint4*>(hbc + (size_t)s1 * 128);
    if (rem > 16) p2 = *reinterpret_cast<const uint4*>(hbc + (size_t)s2 * 128);
    if (rem > 24) p3 = *reinterpret_cast<const uint4*>(hbc + (size_t)s3 * 128);
    float aA = asrc[sA * 4 + hq] + adq;     // coalesced 16B across 4 head lanes
    float aB = asrc[sB * 4 + hq] + adq;
    aA = fmaxf(aA, aA * NEG);
    aB = fmaxf(aB, aB * NEG);
    float wA = (eA < end) ? __expf(aA) : 0.f;
    float wB = (eB < end) ? __expf(aB) : 0.f;
    dsp += wA + wB;
    float w0 = bperm_f(bp0, wA);
    float w1 = bperm_f(bp1, wA);
    float w2 = bperm_f(bp0, wB);
    float w3 = bperm_f(bp1, wB);
    // ---- phase B: consume (guards are wave-uniform) ----
    ACC(p0, w0);
    if (rem > 8)  ACC(p1, w1);
    if (rem > 16) ACC(p2, w2);
    if (rem > 24) ACC(p3, w3);
  }
  // softmax denominator: sum over stride-4 lane groups (per head), then broadcast
  dsp += __shfl_xor(dsp, 4, 64);
  dsp += __shfl_xor(dsp, 8, 64);
  dsp += __shfl_xor(dsp, 16, 64);
  dsp += __shfl_xor(dsp, 32, 64);
  float ds = bperm_f(h << 2, dsp);
  int b3 = (l >> 3) & 1, b4 = (l >> 4) & 1, b5 = (l >> 5) & 1;
  float t8[8];
#pragma unroll
  for (int r = 0; r < 8; r++) {
    float av = a2[r >> 1][r & 1];
    float bv = a2[(r + 8) >> 1][r & 1];
    float send = b3 ? av : bv;
    float recv = __shfl_xor(send, 8, 64);
    t8[r] = (b3 ? bv : av) + recv;
  }
  float t4[4];
#pragma unroll
  for (int r = 0; r < 4; r++) {
    float send = b4 ? t8[r] : t8[r + 4];
    float recv = __shfl_xor(send, 16, 64);
    t4[r] = (b4 ? t8[r + 4] : t8[r]) + recv;
  }
  float t2[2];
#pragma unroll
  for (int r = 0; r < 2; r++) {
    float send = b5 ? t4[r] : t4[r + 2];
    float recv = __shfl_xor(send, 32, 64);
    t2[r] = (b5 ? t4[r + 2] : t4[r]) + recv;
  }
  float inv = __builtin_amdgcn_rcpf(ds > 0.f ? ds : 1.f);
  int c0 = cb * 16 + b3 * 8 + b4 * 4 + b5 * 2;
  float2 bi = *reinterpret_cast<const float2*>(bias + c0);
  float r0 = fmaf(t2[0], inv, bi.x);
  float r1 = fmaf(t2[1], inv, bi.y);
  r0 = r0 > 0.f ? r0 : __expf(r0) - 1.f;   // elu via exp (abs err ~1e-7)
  r1 = r1 > 0.f ? r1 : __expf(r1) - 1.f;
  *reinterpret_cast<uint*>(&rowl[wv][c0]) = cvtpkbf16(r0, r1);
  __syncthreads();
  if (wv != 0) return;
  // ---- gemm2 + att2 on the block's 4 rows (wave 0 only) ----
  int lg = l >> 4, lr = l & 15;
  int rsel = lr & 3;
  bf16x8 bfrag[4];
#pragma unroll
  for (int kc = 0; kc < 4; kc++) {
    U4B bb;
    bb.u = *reinterpret_cast<const uint4*>(&rowl[rsel][kc * 32 + lg * 8]);
    bfrag[kc] = bb.v;
  }
  int dd = blockIdx.x * 4 + lr;      // valid only for lr<4
  bool vs = (lr < 4) && (dd < N);
  float pS = 0.f, pD = 0.f;
#pragma unroll
  for (int ct = 0; ct < 2; ct++) {
    f32x4 acc = {0.f, 0.f, 0.f, 0.f};
    const ushort* wrow = Wt2 + (size_t)(ct * 16 + lr) * 128;
#pragma unroll
    for (int kc = 0; kc < 4; kc++) {
      U4B bfr;
      bfr.u = *reinterpret_cast<const uint4*>(wrow + kc * 32 + lg * 8);
      acc = __builtin_amdgcn_mfma_f32_16x16x32_bf16(bfr.v, bfrag[kc], acc, 0, 0, 0);
    }
    int cg = ct * 16 + lg * 4;
    if (vs) {
      uint u8 = (uint)__builtin_amdgcn_cvt_pk_fp8_f32(acc[0], acc[1], 0, false);
      u8 = (uint)__builtin_amdgcn_cvt_pk_fp8_f32(acc[2], acc[3], u8, true);
      *reinterpret_cast<uint*>(rec2 + (size_t)dd * 64 + cg) = u8;
    }
    float4 as4 = *reinterpret_cast<const float4*>(as2 + cg);
    float4 ad4 = *reinterpret_cast<const float4*>(ad2 + cg);
    pS += acc[0] * as4.x + acc[1] * as4.y + acc[2] * as4.z + acc[3] * as4.w;
    pD += acc[0] * ad4.x + acc[1] * ad4.y + acc[2] * ad4.z + acc[3] * ad4.w;
  }
  pS += __shfl_xor(pS, 16, 64);
  pS += __shfl_xor(pS, 32, 64);
  pD += __shfl_xor(pD, 16, 64);
  pD += __shfl_xor(pD, 32, 64);
  if (vs && lg == 0) {
    *reinterpret_cast<float*>(rec2 + (size_t)dd * 64 + 32) = pS;
    adst2[dd] = pD;
  }
}

// ---- layer-2 aggregation + in-kernel graph pooling ----
// 64-B packed records: phase-A asrc load warms the line phase-B's row load hits.
// Per-block LDS pooling (batch sorted -> <=4 graph slots), then atomics into gsum.
__global__ void k_aggr2(const int* __restrict__ offs, const int* __restrict__ ssrc,
                        const uchar* __restrict__ rec, const float* __restrict__ adst,
                        const float* __restrict__ bias, const int* __restrict__ batch,
                        float* __restrict__ gsum, int N) {
  __shared__ float sblk[4][32];
  int tid = threadIdx.x;
  int wid = tid >> 6, l = tid & 63;
  if (tid < 128) sblk[tid >> 5][tid & 31] = 0.f;
  __syncthreads();
  int d = blockIdx.x * 4 + wid;
  bool valid = d < N;
  int dc = valid ? d : N - 1;
  int slot = l >> 2;       // 0..15 edge slot (phase B)
  int k = l & 3;           // channel block: ch k*8 .. +7
  float ad = adst[dc];
  int beg = offs[dc];
  int end = valid ? offs[dc + 1] : beg;
  int endm1 = end - 1;
  const uchar* rk = rec + k * 8;
  int bq0 = slot << 2;
  int bq1 = (slot + 16) << 2;
  int bq2 = (slot + 32) << 2;
  int bq3 = (slot + 48) << 2;
  f32x2 a2[4] = {};
  float dsp = 0.f;
  auto ACC2 = [&](uint2 p, float w) {
    f32x2 wp = {w, w};
    f32x2 f;
    f = __builtin_amdgcn_cvt_pk_f32_fp8(p.x, false); pkfma(a2[0], f, wp);
    f = __builtin_amdgcn_cvt_pk_f32_fp8(p.x, true);  pkfma(a2[1], f, wp);
    f = __builtin_amdgcn_cvt_pk_f32_fp8(p.y, false); pkfma(a2[2], f, wp);
    f = __builtin_amdgcn_cvt_pk_f32_fp8(p.y, true);  pkfma(a2[3], f, wp);
  };
  for (int base = beg; base < end; base += 64) {
    // phase A: 64 edge-weights, one per lane; asrc packed at row+32 warms the line
    int e = base + l;
    int sL = ssrc[min(e, endm1)];
    int s0 = bperm_i(bq0, sL);
    int s1 = bperm_i(bq1, sL);
    int s2 = bperm_i(bq2, sL);
    int s3 = bperm_i(bq3, sL);
    int rem = end - base;
    float av = *reinterpret_cast<const float*>(rec + (size_t)sL * 64 + 32);
    uint2 p0, p1, p2, p3;
    p0 = *reinterpret_cast<const uint2*>(rk + (size_t)s0 * 64);
    if (rem > 16) p1 = *reinterpret_cast<const uint2*>(rk + (size_t)s1 * 64);
    if (rem > 32) p2 = *reinterpret_cast<const uint2*>(rk + (size_t)s2 * 64);
    if (rem > 48) p3 = *reinterpret_cast<const uint2*>(rk + (size_t)s3 * 64);
    float xv = av + ad;
    xv = fmaxf(xv, xv * NEG);
    float wL = (e < end) ? __expf(xv) : 0.f;
    dsp += wL;
    float w0 = bperm_f(bq0, wL);
    float w1 = bperm_f(bq1, wL);
    float w2 = bperm_f(bq2, wL);
    float w3 = bperm_f(bq3, wL);
    ACC2(p0, w0);
    if (rem > 16) ACC2(p1, w1);
    if (rem > 32) ACC2(p2, w2);
    if (rem > 48) ACC2(p3, w3);
  }
  dsp += __shfl_xor(dsp, 1, 64);
  dsp += __shfl_xor(dsp, 2, 64);
  dsp += __shfl_xor(dsp, 4, 64);
  dsp += __shfl_xor(dsp, 8, 64);
  dsp += __shfl_xor(dsp, 16, 64);
  dsp += __shfl_xor(dsp, 32, 64);
  int b2 = (l >> 2) & 1, b3 = (l >> 3) & 1, b4 = (l >> 4) & 1;
  float t4[4];
#pragma unroll
  for (int r = 0; r < 4; r++) {
    float av = a2[r >> 1][r & 1];
    float bv = a2[(r + 4) >> 1][r & 1];
    float send = b2 ? av : bv;
    float recv = __shfl_xor(send, 4, 64);
    t4[r] = (b2 ? bv : av) + recv;
  }
  float t2[2];
#pragma unroll
  for (int r = 0; r < 2; r++) {
    float send = b3 ? t4[r] : t4[r + 2];
    float recv = __shfl_xor(send, 8, 64);
    t2[r] = (b3 ? t4[r + 2] : t4[r]) + recv;
  }
  float send = b4 ? t2[0] : t2[1];
  float recv = __shfl_xor(send, 16, 64);
  float t1 = (b4 ? t2[1] : t2[0]) + recv;
  t1 += __shfl_xor(t1, 32, 64);
  int gfirst = batch[blockIdx.x * 4];     // first node of block always < N
  if (l < 32 && valid) {
    int c = k * 8 + b2 * 4 + b3 * 2 + b4;
    float inv = __builtin_amdgcn_rcpf(dsp > 0.f ? dsp : 1.f);
    float r = fmaf(t1, inv, bias[c]);
    r = r > 0.f ? r : __expf(r) - 1.f;
    int g = batch[dc];
    int sl = g - gfirst;
    if (sl < 4) atomicAdd(&sblk[sl][c], r);
    else atomicAdd(&gsum[g * 32 + c], r);   // rare: >4 graphs in one block
  }
  __syncthreads();
  if (tid < 128) {
    int sl = tid >> 5, c = tid & 31;
    float v = sblk[sl][c];
    int gg = gfirst + sl;
    if (v != 0.f && gg < NGRAPH) atomicAdd(&gsum[gg * 32 + c], v);
  }
}

// ---------------- k_fc: pooled mean (from gsum + binary-search counts) + FC ----------------
__global__ void k_fc(const float* __restrict__ gsum, const int* __restrict__ batch,
                     const float* __restrict__ fcW, const float* __restrict__ fcb,
                     float* __restrict__ out, int N) {
  int g = blockIdx.x;
  int l = threadIdx.x;
  int lo = 0, hi = N;
  while (lo < hi) { int mid = (lo + hi) >> 1; if (batch[mid] < g) lo = mid + 1; else hi = mid; }
  int beg = lo;
  hi = N;
  while (lo < hi) { int mid = (lo + hi) >> 1; if (batch[mid] < g + 1) lo = mid + 1; else hi = mid; }
  int end = lo;
  float inv = 1.f / fmaxf((float)(end - beg), 1.f);
  __shared__ float pooled[32];
  if (l < 32) pooled[l] = gsum[g * 32 + l] * inv;
  __syncthreads();
  if (l < 16) {
    float r = fcb[l];
#pragma unroll
    for (int cc = 0; cc < 32; cc++) r += pooled[cc] * fcW[cc * 16 + l];
    out[g * 16 + l] = r;
  }
}

// ---------------- host launch ----------------
extern "C" void kernel_launch(void* const* d_in, const int* in_sizes, int n_in,
                              void* d_out, int out_size, void* d_ws, size_t ws_size,
                              hipStream_t stream) {
  const float* x     = (const float*)d_in[0];
  const int*   ei    = (const int*)d_in[1];
  const int*   batch = (const int*)d_in[2];
  const float* nw    = (const float*)d_in[3];
  const float* W1    = (const float*)d_in[4];
  const float* as1w  = (const float*)d_in[5];
  const float* ad1w  = (const float*)d_in[6];
  const float* b1    = (const float*)d_in[7];
  const float* W2    = (const float*)d_in[8];
  const float* as2w  = (const float*)d_in[9];
  const float* ad2w  = (const float*)d_in[10];
  const float* b2    = (const float*)d_in[11];
  const float* fcW   = (const float*)d_in[12];
  const float* fcb   = (const float*)d_in[13];
  float* out = (float*)d_out;

  const int N = in_sizes[0] / 128;
  const int E = in_sizes[1] / 2;
  const int Etot = E + N;
  const int NB = (N + BSZ - 1) >> BSH;

  char* w = (char*)d_ws;
  size_t ofs = 0;
  auto alloc = [&](size_t bytes) {
    char* p = w + ofs;
    ofs += (bytes + 255) & ~(size_t)255;
    return p;
  };
  uchar*  hb1    = (uchar*)alloc((size_t)N * 128);        // fp8 layer-1 features
  uchar*  rec2   = (uchar*)alloc((size_t)N * 64);         // [32B fp8 row | 4B asrc2 | pad]
  float*  asrc1  = (float*)alloc((size_t)N * 4 * 4);
  float*  adst1  = (float*)alloc((size_t)N * 4 * 4);
  float*  adst2  = (float*)alloc((size_t)N * 4);
  ushort* Wt1    = (ushort*)alloc(16384 * 2);
  ushort* Wt2    = (ushort*)alloc(4096 * 2);
  int*    bcur   = (int*)alloc((size_t)NB * 4);
  float*  gsum   = (float*)alloc((size_t)NGRAPH * 32 * 4);
  int*    offs   = (int*)alloc((size_t)(N + 1) * 4);
  uint*   bbuf   = (uint*)alloc((size_t)NB * CAP * 4);
  int*    ssrc   = (int*)alloc((size_t)Etot * 4);

  // one memset zeroes bcur + gsum (allocated adjacently)
  size_t zlen = (size_t)((char*)gsum - (char*)bcur) + (size_t)NGRAPH * 32 * 4;
  hipMemsetAsync(bcur, 0, zlen, stream);

  // binned CSR: hist + LDS counting sort + coalesced scatter (+W1/W2 prep folded in)
  const int nbin = (Etot + CH - 1) / CH;
  k_bin<<<nbin + 80, 256, 0, stream>>>(ei, W1, W2, Wt1, Wt2, E, Etot, NB, nbin, bcur, bbuf);

  // build ‖ gemm1 (independent): blocks [0,NB) build CSR, rest run GEMM1+att1
  const int ngemm1 = (N + 63) / 64;
  k_bg<<<NB + ngemm1, 256, 0, stream>>>(bbuf, bcur, NB, N, offs, ssrc,
                                        x, Wt1, nw, as1w, ad1w, hb1, asrc1, adst1);

  // fused: layer-1 aggregation + layer-2 GEMM (MFMA) + att2 -> packed rec2
  k_aggr1<<<(N + 3) / 4, 256, 0, stream>>>(offs, ssrc, hb1, asrc1, adst1, b1,
                                           Wt2, as2w, ad2w, rec2, adst2, N);

  // layer-2 aggregation + in-kernel pooling
  k_aggr2<<<(N + 3) / 4, 256, 0, stream>>>(offs, ssrc, rec2, adst2, b2, batch, gsum, N);

  // pooled mean + fc (tiny)
  k_fc<<<NGRAPH, 64, 0, stream>>>(gsum, batch, fcW, fcb, out, N);
}